// Round 1
// baseline (2663.872 us; speedup 1.0000x reference)
//
#include <hip/hip_runtime.h>
#include <math.h>

#define N_NODES 100000
#define N_EDGES 1600000
#define N_GRAPHS 2048
#define NCLS 204
#define EPS_BN 1e-5f

// ---------------- CSR build ----------------
__global__ void k_degree(const int* __restrict__ dst, int* __restrict__ deg, int E) {
  int i = blockIdx.x * blockDim.x + threadIdx.x;
  if (i < E) atomicAdd(&deg[dst[i]], 1);
}

__global__ __launch_bounds__(1024) void k_scan(const int* __restrict__ deg,
                                               int* __restrict__ row_ptr,
                                               int n, int total) {
  __shared__ int part[1024];
  int t = threadIdx.x;
  int chunk = (n + 1023) / 1024;
  int lo = t * chunk;
  int hi = min(lo + chunk, n);
  int s = 0;
  for (int i = lo; i < hi; i++) s += deg[i];
  part[t] = s;
  __syncthreads();
  for (int d = 1; d < 1024; d <<= 1) {
    int v = (t >= d) ? part[t - d] : 0;
    __syncthreads();
    part[t] += v;
    __syncthreads();
  }
  int run = (t == 0) ? 0 : part[t - 1];
  for (int i = lo; i < hi; i++) { row_ptr[i] = run; run += deg[i]; }
  if (t == 0) row_ptr[n] = total;
}

__global__ void k_scatter(const int* __restrict__ src, const int* __restrict__ dst,
                          int* __restrict__ cursor, int* __restrict__ csr_src, int E) {
  int i = blockIdx.x * blockDim.x + threadIdx.x;
  if (i < E) {
    int p = atomicAdd(&cursor[dst[i]], 1);
    csr_src[p] = src[i];
  }
}

// ---------------- GIN aggregation: M = 2*x + sum_{src->n} x[src] ----------------
__global__ void k_agg(const float* __restrict__ x, const int* __restrict__ row_ptr,
                      const int* __restrict__ csr_src, float* __restrict__ M, int C) {
  int n = blockIdx.x;
  int c = threadIdx.x;
  if (c >= C) return;
  float acc = 2.0f * x[(size_t)n * C + c];
  int s = row_ptr[n], e = row_ptr[n + 1];
  for (int i = s; i < e; i++) acc += x[(size_t)csr_src[i] * C + c];
  M[(size_t)n * C + c] = acc;
}

// ---------------- generic fp32 GEMM: Y[M x ncols] = A[M x K] * W[:, col_off:col_off+ncols] + bscale*bias ----------------
#define KTILE 128
__global__ __launch_bounds__(256) void k_gemm(const float* __restrict__ A, int lda,
                                              int Mrows, int K,
                                              const float* __restrict__ W, int wld,
                                              int col_off,
                                              const float* __restrict__ bias, float bscale,
                                              float* __restrict__ Y, int ncols) {
  __shared__ float At[KTILE][36];   // [k][row], padded
  __shared__ float Ws[KTILE][64];   // [k][col]
  int t = threadIdx.x;
  int tx = t & 31;        // 32 col-groups of 2
  int ty = t >> 5;        // 8 row-groups of 4
  int r0 = blockIdx.y * 32;
  int c0 = blockIdx.x * 64;
  float acc[4][2] = {};

  for (int k0 = 0; k0 < K; k0 += KTILE) {
    int kt = min(KTILE, K - k0);
    for (int e = t; e < 32 * kt; e += 256) {
      int r = e / kt, k = e - r * kt;
      int gr = r0 + r;
      At[k][r] = (gr < Mrows) ? A[(size_t)gr * lda + k0 + k] : 0.0f;
    }
    for (int e = t; e < kt * 64; e += 256) {
      int k = e >> 6, c = e & 63;
      int gc = c0 + c;
      Ws[k][c] = (gc < ncols) ? W[(size_t)(k0 + k) * wld + col_off + gc] : 0.0f;
    }
    __syncthreads();
    for (int k = 0; k < kt; k++) {
      float4 a = *reinterpret_cast<const float4*>(&At[k][ty * 4]);
      float2 w = *reinterpret_cast<const float2*>(&Ws[k][tx * 2]);
      acc[0][0] += a.x * w.x; acc[0][1] += a.x * w.y;
      acc[1][0] += a.y * w.x; acc[1][1] += a.y * w.y;
      acc[2][0] += a.z * w.x; acc[2][1] += a.z * w.y;
      acc[3][0] += a.w * w.x; acc[3][1] += a.w * w.y;
    }
    __syncthreads();
  }

  for (int i = 0; i < 4; i++) {
    int r = r0 + ty * 4 + i;
    if (r >= Mrows) continue;
    for (int j = 0; j < 2; j++) {
      int c = c0 + tx * 2 + j;
      if (c < ncols)
        Y[(size_t)r * ncols + c] = acc[i][j] + bscale * bias[col_off + c];
    }
  }
}

// ---------------- BN stats: per-channel sum & sumsq ----------------
__global__ void k_stats(const float* __restrict__ Y, int Mrows, int C,
                        float* __restrict__ sum, float* __restrict__ sumsq) {
  int c = threadIdx.x;  // blockDim.x == C
  float s = 0.0f, q = 0.0f;
  for (int r = blockIdx.x; r < Mrows; r += gridDim.x) {
    float v = Y[(size_t)r * C + c];
    s += v;
    q += v * v;
  }
  atomicAdd(&sum[c], s);
  atomicAdd(&sumsq[c], q);
}

__global__ void k_bnparams(const float* __restrict__ sum, const float* __restrict__ sumsq,
                           const float* __restrict__ gamma, const float* __restrict__ beta,
                           float* __restrict__ Ac, float* __restrict__ Bc,
                           int C, float invM) {
  int c = blockIdx.x * blockDim.x + threadIdx.x;
  if (c < C) {
    float mu = sum[c] * invM;
    float var = sumsq[c] * invM - mu * mu;
    float rs = rsqrtf(var + EPS_BN);
    float a = gamma[c] * rs;
    Ac[c] = a;
    Bc[c] = beta[c] - mu * a;
  }
}

// ---------------- normalize + relu ----------------
__global__ void k_norm_relu(const float* __restrict__ Y, const float* __restrict__ Ac,
                            const float* __restrict__ Bc, float* __restrict__ X,
                            int total, int cmask) {
  int i = (blockIdx.x * blockDim.x + threadIdx.x) * 4;
  if (i < total) {
    float4 v = *reinterpret_cast<const float4*>(&Y[i]);
    int c = i & cmask;
    v.x = fmaxf(v.x * Ac[c] + Bc[c], 0.0f);
    v.y = fmaxf(v.y * Ac[c + 1] + Bc[c + 1], 0.0f);
    v.z = fmaxf(v.z * Ac[c + 2] + Bc[c + 2], 0.0f);
    v.w = fmaxf(v.w * Ac[c + 3] + Bc[c + 3], 0.0f);
    *reinterpret_cast<float4*>(&X[i]) = v;
  }
}

// ---------------- graph readout (segment sum) ----------------
__global__ void k_readout(const float* __restrict__ x, const int* __restrict__ gid,
                          float* __restrict__ xg) {
  int n = blockIdx.x;
  int c = threadIdx.x;
  atomicAdd(&xg[(size_t)gid[n] * 128 + c], x[(size_t)n * 128 + c]);
}

// ---------------- sigmoid ----------------
__global__ void k_sigmoid(const float* __restrict__ y, float* __restrict__ out, int total) {
  int i = blockIdx.x * blockDim.x + threadIdx.x;
  if (i < total) out[i] = 1.0f / (1.0f + expf(-y[i]));
}

extern "C" void kernel_launch(void* const* d_in, const int* in_sizes, int n_in,
                              void* d_out, int out_size, void* d_ws, size_t ws_size,
                              hipStream_t stream) {
  const float* h    = (const float*)d_in[0];
  const int*   esrc = (const int*)d_in[1];
  const int*   edst = (const int*)d_in[2];
  const int*   gid  = (const int*)d_in[3];
  const float* W1   = (const float*)d_in[4];
  const float* b1   = (const float*)d_in[5];
  const float* g1g  = (const float*)d_in[6];
  const float* g1b  = (const float*)d_in[7];
  const float* Wg   = (const float*)d_in[8];
  const float* bg   = (const float*)d_in[9];
  const float* gg   = (const float*)d_in[10];
  const float* gb   = (const float*)d_in[11];
  const float* fc1W = (const float*)d_in[12];
  const float* fc1b = (const float*)d_in[13];
  const float* bn1g = (const float*)d_in[14];
  const float* bn1b = (const float*)d_in[15];
  const float* linW = (const float*)d_in[16];
  const float* linb = (const float*)d_in[17];
  const float* lbng = (const float*)d_in[18];
  const float* lbnb = (const float*)d_in[19];
  const float* fc2W = (const float*)d_in[20];
  const float* fc2b = (const float*)d_in[21];
  float* out = (float*)d_out;

  char* p = (char*)d_ws;
  auto alloc = [&](size_t bytes) {
    char* q = p;
    p += (bytes + 255) & ~(size_t)255;
    return q;
  };
  int* row_ptr = (int*)alloc((N_NODES + 1) * sizeof(int));
  int* cursor  = (int*)alloc(N_NODES * sizeof(int));   // also used as degree
  int* csr     = (int*)alloc(N_EDGES * sizeof(int));
  float* xb    = (float*)alloc((size_t)N_NODES * 128 * sizeof(float));
  float* Mb    = (float*)alloc((size_t)N_NODES * 128 * sizeof(float));
  float* yb    = (float*)alloc((size_t)N_NODES * 128 * sizeof(float));
  float* ssum  = (float*)alloc(512 * sizeof(float));
  float* ssq   = (float*)alloc(512 * sizeof(float));
  float* Ac    = (float*)alloc(512 * sizeof(float));
  float* Bc    = (float*)alloc(512 * sizeof(float));
  float* xg    = (float*)alloc((size_t)N_GRAPHS * 128 * sizeof(float));
  // MLP temporaries aliased into Mb (free after readout)
  float* y1   = (float*)Mb;                       // G x 512
  float* x1   = y1 + (size_t)N_GRAPHS * 512;      // G x 512
  float* y2   = x1 + (size_t)N_GRAPHS * 512;      // G x 256
  float* x2   = y2 + (size_t)N_GRAPHS * 256;      // G x 256
  float* ylog = x2 + (size_t)N_GRAPHS * 256;      // G x 204

  // ---- CSR build ----
  hipMemsetAsync(cursor, 0, N_NODES * sizeof(int), stream);
  k_degree<<<(N_EDGES + 255) / 256, 256, 0, stream>>>(edst, cursor, N_EDGES);
  k_scan<<<1, 1024, 0, stream>>>(cursor, row_ptr, N_NODES, N_EDGES);
  hipMemcpyAsync(cursor, row_ptr, N_NODES * sizeof(int), hipMemcpyDeviceToDevice, stream);
  k_scatter<<<(N_EDGES + 255) / 256, 256, 0, stream>>>(esrc, edst, cursor, csr, N_EDGES);

  const float invN = 1.0f / (float)N_NODES;
  const float invG = 1.0f / (float)N_GRAPHS;

  // ---- GIN layer 1 (78 -> 128) ----
  k_agg<<<N_NODES, 128, 0, stream>>>(h, row_ptr, csr, Mb, 78);
  {
    dim3 grid(2, (N_NODES + 31) / 32);
    k_gemm<<<grid, 256, 0, stream>>>(Mb, 78, N_NODES, 78, W1, 128, 0, b1, 2.0f, yb, 128);
  }
  hipMemsetAsync(ssum, 0, 128 * sizeof(float), stream);
  hipMemsetAsync(ssq, 0, 128 * sizeof(float), stream);
  k_stats<<<256, 128, 0, stream>>>(yb, N_NODES, 128, ssum, ssq);
  k_bnparams<<<1, 128, 0, stream>>>(ssum, ssq, g1g, g1b, Ac, Bc, 128, invN);
  k_norm_relu<<<(N_NODES * 128 / 4 + 255) / 256, 256, 0, stream>>>(yb, Ac, Bc, xb,
                                                                   N_NODES * 128, 127);

  // ---- GIN layers 2..5 (128 -> 128) ----
  for (int l = 0; l < 4; l++) {
    k_agg<<<N_NODES, 128, 0, stream>>>(xb, row_ptr, csr, Mb, 128);
    dim3 grid(2, (N_NODES + 31) / 32);
    k_gemm<<<grid, 256, 0, stream>>>(Mb, 128, N_NODES, 128, Wg + (size_t)l * 128 * 128, 128,
                                     0, bg + (size_t)l * 128, 2.0f, yb, 128);
    hipMemsetAsync(ssum, 0, 128 * sizeof(float), stream);
    hipMemsetAsync(ssq, 0, 128 * sizeof(float), stream);
    k_stats<<<256, 128, 0, stream>>>(yb, N_NODES, 128, ssum, ssq);
    k_bnparams<<<1, 128, 0, stream>>>(ssum, ssq, gg + (size_t)l * 128, gb + (size_t)l * 128,
                                      Ac, Bc, 128, invN);
    k_norm_relu<<<(N_NODES * 128 / 4 + 255) / 256, 256, 0, stream>>>(yb, Ac, Bc, xb,
                                                                     N_NODES * 128, 127);
  }

  // ---- readout ----
  hipMemsetAsync(xg, 0, (size_t)N_GRAPHS * 128 * sizeof(float), stream);
  k_readout<<<N_NODES, 128, 0, stream>>>(xb, gid, xg);

  // ---- fc1 (128 -> 512) + BN + relu ----
  {
    dim3 grid(8, N_GRAPHS / 32);
    k_gemm<<<grid, 256, 0, stream>>>(xg, 128, N_GRAPHS, 128, fc1W, 512, 0, fc1b, 1.0f, y1, 512);
  }
  hipMemsetAsync(ssum, 0, 512 * sizeof(float), stream);
  hipMemsetAsync(ssq, 0, 512 * sizeof(float), stream);
  k_stats<<<256, 512, 0, stream>>>(y1, N_GRAPHS, 512, ssum, ssq);
  k_bnparams<<<1, 512, 0, stream>>>(ssum, ssq, bn1g, bn1b, Ac, Bc, 512, invG);
  k_norm_relu<<<(N_GRAPHS * 512 / 4 + 255) / 256, 256, 0, stream>>>(y1, Ac, Bc, x1,
                                                                    N_GRAPHS * 512, 511);

  // ---- lin (512 -> 256) + BN + relu ----
  {
    dim3 grid(4, N_GRAPHS / 32);
    k_gemm<<<grid, 256, 0, stream>>>(x1, 512, N_GRAPHS, 512, linW, 256, 0, linb, 1.0f, y2, 256);
  }
  hipMemsetAsync(ssum, 0, 256 * sizeof(float), stream);
  hipMemsetAsync(ssq, 0, 256 * sizeof(float), stream);
  k_stats<<<256, 256, 0, stream>>>(y2, N_GRAPHS, 256, ssum, ssq);
  k_bnparams<<<1, 256, 0, stream>>>(ssum, ssq, lbng, lbnb, Ac, Bc, 256, invG);
  k_norm_relu<<<(N_GRAPHS * 256 / 4 + 255) / 256, 256, 0, stream>>>(y2, Ac, Bc, x2,
                                                                    N_GRAPHS * 256, 255);

  // ---- fc2, only last 204 columns, + sigmoid ----
  {
    dim3 grid((NCLS + 63) / 64, N_GRAPHS / 32);
    k_gemm<<<grid, 256, 0, stream>>>(x2, 256, N_GRAPHS, 256, fc2W, 408, 204, fc2b, 1.0f,
                                     ylog, NCLS);
  }
  {
    int total = N_GRAPHS * NCLS;
    k_sigmoid<<<(total + 255) / 256, 256, 0, stream>>>(ylog, out, total);
  }
}

// Round 2
// 1820.960 us; speedup vs baseline: 1.4629x; 1.4629x over previous
//
#include <hip/hip_runtime.h>
#include <hip/hip_bf16.h>
#include <math.h>

#define N_NODES 100000
#define N_EDGES 1600000
#define N_GRAPHS 2048
#define NCLS 204
#define EPS_BN 1e-5f

typedef __attribute__((ext_vector_type(8))) short short8;
typedef __attribute__((ext_vector_type(4))) float f32x4;

__device__ __forceinline__ float bf_lo(uint v) { union { uint i; float f; } c; c.i = v << 16; return c.f; }
__device__ __forceinline__ float bf_hi(uint v) { union { uint i; float f; } c; c.i = v & 0xffff0000u; return c.f; }
__device__ __forceinline__ ushort f2bf(float v) {
  __hip_bfloat16 b = __float2bfloat16(v);
  return *reinterpret_cast<ushort*>(&b);
}
__device__ __forceinline__ uint pack2(float a, float b) {
  return (uint)f2bf(a) | ((uint)f2bf(b) << 16);
}

// ---------------- CSR build ----------------
__global__ void k_degree(const int* __restrict__ dst, int* __restrict__ deg, int E) {
  int i = blockIdx.x * blockDim.x + threadIdx.x;
  if (i < E) atomicAdd(&deg[dst[i]], 1);
}

__global__ __launch_bounds__(1024) void k_scan(const int* __restrict__ deg,
                                               int* __restrict__ row_ptr,
                                               int n, int total) {
  __shared__ int part[1024];
  int t = threadIdx.x;
  int chunk = (n + 1023) / 1024;
  int lo = t * chunk;
  int hi = min(lo + chunk, n);
  int s = 0;
  for (int i = lo; i < hi; i++) s += deg[i];
  part[t] = s;
  __syncthreads();
  for (int d = 1; d < 1024; d <<= 1) {
    int v = (t >= d) ? part[t - d] : 0;
    __syncthreads();
    part[t] += v;
    __syncthreads();
  }
  int run = (t == 0) ? 0 : part[t - 1];
  for (int i = lo; i < hi; i++) { row_ptr[i] = run; run += deg[i]; }
  if (t == 0) row_ptr[n] = total;
}

__global__ void k_scatter(const int* __restrict__ src, const int* __restrict__ dst,
                          int* __restrict__ cursor, int* __restrict__ csr_src, int E) {
  int i = blockIdx.x * blockDim.x + threadIdx.x;
  if (i < E) {
    int p = atomicAdd(&cursor[dst[i]], 1);
    csr_src[p] = src[i];
  }
}

// ---------------- conversions / weight prep ----------------
// h [N x 78] fp32 -> hb [N x 128] bf16 (zero-padded), packed as uint pairs
__global__ void k_conv_h(const float* __restrict__ h, uint* __restrict__ hb, int nNodes) {
  int i = blockIdx.x * blockDim.x + threadIdx.x;
  if (i < nNodes * 64) {
    int n = i >> 6, cp = i & 63;
    int c = cp * 2;
    float a = (c < 78) ? h[(size_t)n * 78 + c] : 0.0f;
    float b = (c + 1 < 78) ? h[(size_t)n * 78 + c + 1] : 0.0f;
    hb[i] = pack2(a, b);
  }
}

// W [K x 128] fp32 -> Wt [128 x 128] bf16 transposed (Wt[n][k]), zero pad k>=K
__global__ void k_prep_wt(const float* __restrict__ W, ushort* __restrict__ Wt, int K) {
  int i = blockIdx.x * blockDim.x + threadIdx.x;
  if (i < 128 * 128) {
    int n = i >> 7, k = i & 127;
    float v = (k < K) ? W[(size_t)k * 128 + n] : 0.0f;
    Wt[i] = f2bf(v);
  }
}

// ---------------- GIN aggregation (bf16): M = 2*x + sum_{src->n} x[src] ----------------
__global__ __launch_bounds__(256) void k_agg(const uint* __restrict__ x,
                                             const int* __restrict__ row_ptr,
                                             const int* __restrict__ csr,
                                             uint* __restrict__ M, int nNodes) {
  int n = blockIdx.x * 4 + (threadIdx.x >> 6);
  if (n >= nNodes) return;
  int l = threadIdx.x & 63;
  uint self = x[(size_t)n * 64 + l];
  float a0 = 2.0f * bf_lo(self);
  float a1 = 2.0f * bf_hi(self);
  int s = row_ptr[n], e = row_ptr[n + 1];
  for (int i = s; i < e; i++) {
    int src = csr[i];
    uint v = x[(size_t)src * 64 + l];
    a0 += bf_lo(v);
    a1 += bf_hi(v);
  }
  M[(size_t)n * 64 + l] = pack2(a0, a1);
}

// ---------------- MFMA GEMM: Y[M x 128] = A[M x 128] * Wt^T + bscale*bias (all bf16 in, bf16 out) ----------------
#define SWZ(row, boff) ((boff) ^ (((row) & 7) << 4))
__global__ __launch_bounds__(256) void k_gemm_mfma(const ushort* __restrict__ A,
                                                   const ushort* __restrict__ Wt,
                                                   const float* __restrict__ bias, float bscale,
                                                   ushort* __restrict__ Y, int Mrows) {
  __shared__ ushort As[128 * 128];
  __shared__ ushort Bs[128 * 128];
  int t = threadIdx.x;
  int r0 = blockIdx.x * 128;
  char* Ab = (char*)As;
  char* Bb = (char*)Bs;

  // stage A (guarded) and Wt, 16B per thread per iter, XOR-swizzled dest
  for (int it = 0; it < 8; it++) {
    int e = it * 256 + t;
    int row = e >> 4, seg = e & 15;
    uint4 va = make_uint4(0, 0, 0, 0);
    int gr = r0 + row;
    if (gr < Mrows) va = *reinterpret_cast<const uint4*>(A + (size_t)gr * 128 + seg * 8);
    *reinterpret_cast<uint4*>(Ab + row * 256 + SWZ(row, seg * 16)) = va;
    uint4 vb = *reinterpret_cast<const uint4*>(Wt + (size_t)row * 128 + seg * 8);
    *reinterpret_cast<uint4*>(Bb + row * 256 + SWZ(row, seg * 16)) = vb;
  }
  __syncthreads();

  int wi = t >> 6;       // wave 0..3 -> rows wi*32..wi*32+31
  int l = t & 63;
  int lr = l & 15;
  int kp = l >> 4;       // 0..3

  f32x4 acc[2][8];
#pragma unroll
  for (int mi = 0; mi < 2; mi++)
#pragma unroll
    for (int ni = 0; ni < 8; ni++) acc[mi][ni] = (f32x4){0.f, 0.f, 0.f, 0.f};

#pragma unroll
  for (int ki = 0; ki < 4; ki++) {
    short8 a[2], b[8];
#pragma unroll
    for (int mi = 0; mi < 2; mi++) {
      int row = wi * 32 + mi * 16 + lr;
      a[mi] = *reinterpret_cast<const short8*>(Ab + row * 256 + SWZ(row, ki * 64 + kp * 16));
    }
#pragma unroll
    for (int ni = 0; ni < 8; ni++) {
      int row = ni * 16 + lr;
      b[ni] = *reinterpret_cast<const short8*>(Bb + row * 256 + SWZ(row, ki * 64 + kp * 16));
    }
#pragma unroll
    for (int mi = 0; mi < 2; mi++)
#pragma unroll
      for (int ni = 0; ni < 8; ni++)
        acc[mi][ni] = __builtin_amdgcn_mfma_f32_16x16x32_bf16(a[mi], b[ni], acc[mi][ni], 0, 0, 0);
  }

  // epilogue: C layout col=lane&15, row=(lane>>4)*4+j
#pragma unroll
  for (int mi = 0; mi < 2; mi++) {
    int rbase = r0 + wi * 32 + mi * 16 + kp * 4;
#pragma unroll
    for (int ni = 0; ni < 8; ni++) {
      int col = ni * 16 + lr;
      float bb = bscale * bias[col];
#pragma unroll
      for (int j = 0; j < 4; j++) {
        int r = rbase + j;
        if (r < Mrows) Y[(size_t)r * 128 + col] = f2bf(acc[mi][ni][j] + bb);
      }
    }
  }
}

// ---------------- BN stats on bf16 [M x 128] ----------------
__global__ __launch_bounds__(256) void k_stats_bf(const uint* __restrict__ Y, int Mrows,
                                                  float* __restrict__ sum, float* __restrict__ sq) {
  int t = threadIdx.x;
  int cp = t & 63;
  float s0 = 0, s1 = 0, q0 = 0, q1 = 0;
  for (int r = blockIdx.x * 4 + (t >> 6); r < Mrows; r += gridDim.x * 4) {
    uint v = Y[(size_t)r * 64 + cp];
    float a = bf_lo(v), b = bf_hi(v);
    s0 += a; q0 += a * a;
    s1 += b; q1 += b * b;
  }
  __shared__ float ls[4][128], lq[4][128];
  int w = t >> 6;
  ls[w][2 * cp] = s0; ls[w][2 * cp + 1] = s1;
  lq[w][2 * cp] = q0; lq[w][2 * cp + 1] = q1;
  __syncthreads();
  if (t < 128) {
    float S = ls[0][t] + ls[1][t] + ls[2][t] + ls[3][t];
    float Q = lq[0][t] + lq[1][t] + lq[2][t] + lq[3][t];
    atomicAdd(&sum[t], S);
    atomicAdd(&sq[t], Q);
  }
}

__global__ void k_bnparams(const float* __restrict__ sum, const float* __restrict__ sumsq,
                           const float* __restrict__ gamma, const float* __restrict__ beta,
                           float* __restrict__ Ac, float* __restrict__ Bc,
                           int C, float invM) {
  int c = blockIdx.x * blockDim.x + threadIdx.x;
  if (c < C) {
    float mu = sum[c] * invM;
    float var = sumsq[c] * invM - mu * mu;
    float rs = rsqrtf(var + EPS_BN);
    float a = gamma[c] * rs;
    Ac[c] = a;
    Bc[c] = beta[c] - mu * a;
  }
}

// ---------------- normalize + relu (bf16 -> bf16) ----------------
__global__ void k_norm_relu_bf(const uint* __restrict__ Y, const float* __restrict__ Ac,
                               const float* __restrict__ Bc, uint* __restrict__ X, int nu) {
  int i = blockIdx.x * blockDim.x + threadIdx.x;
  if (i < nu) {
    uint v = Y[i];
    int c = (i & 63) * 2;
    float a = fmaxf(bf_lo(v) * Ac[c] + Bc[c], 0.0f);
    float b = fmaxf(bf_hi(v) * Ac[c + 1] + Bc[c + 1], 0.0f);
    X[i] = pack2(a, b);
  }
}

// ---------------- graph readout (sorted gid run-length, bf16 in, fp32 out) ----------------
__global__ __launch_bounds__(64) void k_readout_bf(const uint* __restrict__ x,
                                                   const int* __restrict__ gid,
                                                   float* __restrict__ xg, int nNodes) {
  int l = threadIdx.x;
  int n0 = blockIdx.x * 256;
  int n1 = min(n0 + 256, nNodes);
  if (n0 >= nNodes) return;
  float a0 = 0, a1 = 0;
  int cur = gid[n0];
  for (int n = n0; n < n1; n++) {
    int g = gid[n];
    if (g != cur) {
      atomicAdd(&xg[(size_t)cur * 128 + 2 * l], a0);
      atomicAdd(&xg[(size_t)cur * 128 + 2 * l + 1], a1);
      a0 = 0; a1 = 0; cur = g;
    }
    uint v = x[(size_t)n * 64 + l];
    a0 += bf_lo(v);
    a1 += bf_hi(v);
  }
  atomicAdd(&xg[(size_t)cur * 128 + 2 * l], a0);
  atomicAdd(&xg[(size_t)cur * 128 + 2 * l + 1], a1);
}

// ---------------- generic fp32 GEMM for MLP head ----------------
#define KTILE 128
__global__ __launch_bounds__(256) void k_gemm(const float* __restrict__ A, int lda,
                                              int Mrows, int K,
                                              const float* __restrict__ W, int wld,
                                              int col_off,
                                              const float* __restrict__ bias, float bscale,
                                              float* __restrict__ Y, int ncols) {
  __shared__ float At[KTILE][36];
  __shared__ float Ws[KTILE][64];
  int t = threadIdx.x;
  int tx = t & 31;
  int ty = t >> 5;
  int r0 = blockIdx.y * 32;
  int c0 = blockIdx.x * 64;
  float acc[4][2] = {};

  for (int k0 = 0; k0 < K; k0 += KTILE) {
    int kt = min(KTILE, K - k0);
    for (int e = t; e < 32 * kt; e += 256) {
      int r = e / kt, k = e - r * kt;
      int gr = r0 + r;
      At[k][r] = (gr < Mrows) ? A[(size_t)gr * lda + k0 + k] : 0.0f;
    }
    for (int e = t; e < kt * 64; e += 256) {
      int k = e >> 6, c = e & 63;
      int gc = c0 + c;
      Ws[k][c] = (gc < ncols) ? W[(size_t)(k0 + k) * wld + col_off + gc] : 0.0f;
    }
    __syncthreads();
    for (int k = 0; k < kt; k++) {
      float4 a = *reinterpret_cast<const float4*>(&At[k][ty * 4]);
      float2 w = *reinterpret_cast<const float2*>(&Ws[k][tx * 2]);
      acc[0][0] += a.x * w.x; acc[0][1] += a.x * w.y;
      acc[1][0] += a.y * w.x; acc[1][1] += a.y * w.y;
      acc[2][0] += a.z * w.x; acc[2][1] += a.z * w.y;
      acc[3][0] += a.w * w.x; acc[3][1] += a.w * w.y;
    }
    __syncthreads();
  }

  for (int i = 0; i < 4; i++) {
    int r = r0 + ty * 4 + i;
    if (r >= Mrows) continue;
    for (int j = 0; j < 2; j++) {
      int c = c0 + tx * 2 + j;
      if (c < ncols)
        Y[(size_t)r * ncols + c] = acc[i][j] + bscale * bias[col_off + c];
    }
  }
}

// ---------------- BN stats fp32 (head) ----------------
__global__ void k_stats(const float* __restrict__ Y, int Mrows, int C,
                        float* __restrict__ sum, float* __restrict__ sumsq) {
  int c = threadIdx.x;
  float s = 0.0f, q = 0.0f;
  for (int r = blockIdx.x; r < Mrows; r += gridDim.x) {
    float v = Y[(size_t)r * C + c];
    s += v;
    q += v * v;
  }
  atomicAdd(&sum[c], s);
  atomicAdd(&sumsq[c], q);
}

__global__ void k_norm_relu(const float* __restrict__ Y, const float* __restrict__ Ac,
                            const float* __restrict__ Bc, float* __restrict__ X,
                            int total, int cmask) {
  int i = (blockIdx.x * blockDim.x + threadIdx.x) * 4;
  if (i < total) {
    float4 v = *reinterpret_cast<const float4*>(&Y[i]);
    int c = i & cmask;
    v.x = fmaxf(v.x * Ac[c] + Bc[c], 0.0f);
    v.y = fmaxf(v.y * Ac[c + 1] + Bc[c + 1], 0.0f);
    v.z = fmaxf(v.z * Ac[c + 2] + Bc[c + 2], 0.0f);
    v.w = fmaxf(v.w * Ac[c + 3] + Bc[c + 3], 0.0f);
    *reinterpret_cast<float4*>(&X[i]) = v;
  }
}

__global__ void k_sigmoid(const float* __restrict__ y, float* __restrict__ out, int total) {
  int i = blockIdx.x * blockDim.x + threadIdx.x;
  if (i < total) out[i] = 1.0f / (1.0f + expf(-y[i]));
}

extern "C" void kernel_launch(void* const* d_in, const int* in_sizes, int n_in,
                              void* d_out, int out_size, void* d_ws, size_t ws_size,
                              hipStream_t stream) {
  const float* h    = (const float*)d_in[0];
  const int*   esrc = (const int*)d_in[1];
  const int*   edst = (const int*)d_in[2];
  const int*   gid  = (const int*)d_in[3];
  const float* W1   = (const float*)d_in[4];
  const float* b1   = (const float*)d_in[5];
  const float* g1g  = (const float*)d_in[6];
  const float* g1b  = (const float*)d_in[7];
  const float* Wg   = (const float*)d_in[8];
  const float* bg   = (const float*)d_in[9];
  const float* gg   = (const float*)d_in[10];
  const float* gb   = (const float*)d_in[11];
  const float* fc1W = (const float*)d_in[12];
  const float* fc1b = (const float*)d_in[13];
  const float* bn1g = (const float*)d_in[14];
  const float* bn1b = (const float*)d_in[15];
  const float* linW = (const float*)d_in[16];
  const float* linb = (const float*)d_in[17];
  const float* lbng = (const float*)d_in[18];
  const float* lbnb = (const float*)d_in[19];
  const float* fc2W = (const float*)d_in[20];
  const float* fc2b = (const float*)d_in[21];
  float* out = (float*)d_out;

  char* p = (char*)d_ws;
  auto alloc = [&](size_t bytes) {
    char* q = p;
    p += (bytes + 255) & ~(size_t)255;
    return q;
  };
  int* row_ptr = (int*)alloc((N_NODES + 1) * sizeof(int));
  int* cursor  = (int*)alloc(N_NODES * sizeof(int));
  int* csr     = (int*)alloc(N_EDGES * sizeof(int));
  uint* hb     = (uint*)alloc((size_t)N_NODES * 64 * sizeof(uint));   // bf16 x2
  uint* xb     = (uint*)alloc((size_t)N_NODES * 64 * sizeof(uint));
  uint* Mb     = (uint*)alloc((size_t)N_NODES * 64 * sizeof(uint));
  uint* yb     = (uint*)alloc((size_t)N_NODES * 64 * sizeof(uint));
  ushort* Wt   = (ushort*)alloc(5 * 128 * 128 * sizeof(ushort));
  float* ssum  = (float*)alloc(512 * sizeof(float));
  float* ssq   = (float*)alloc(512 * sizeof(float));
  float* Ac    = (float*)alloc(512 * sizeof(float));
  float* Bc    = (float*)alloc(512 * sizeof(float));
  float* xg    = (float*)alloc((size_t)N_GRAPHS * 128 * sizeof(float));
  // head temps aliased onto Mb (free after node layers)
  float* y1   = (float*)Mb;                       // G x 512
  float* x1   = y1 + (size_t)N_GRAPHS * 512;
  float* y2   = x1 + (size_t)N_GRAPHS * 512;      // G x 256
  float* x2   = y2 + (size_t)N_GRAPHS * 256;
  float* ylog = x2 + (size_t)N_GRAPHS * 256;      // G x 204

  // ---- prep: conversions + CSR build ----
  k_conv_h<<<(N_NODES * 64 + 255) / 256, 256, 0, stream>>>(h, hb, N_NODES);
  k_prep_wt<<<64, 256, 0, stream>>>(W1, Wt, 78);
  for (int l = 0; l < 4; l++)
    k_prep_wt<<<64, 256, 0, stream>>>(Wg + (size_t)l * 128 * 128, Wt + (size_t)(l + 1) * 128 * 128, 128);

  hipMemsetAsync(cursor, 0, N_NODES * sizeof(int), stream);
  k_degree<<<(N_EDGES + 255) / 256, 256, 0, stream>>>(edst, cursor, N_EDGES);
  k_scan<<<1, 1024, 0, stream>>>(cursor, row_ptr, N_NODES, N_EDGES);
  hipMemcpyAsync(cursor, row_ptr, N_NODES * sizeof(int), hipMemcpyDeviceToDevice, stream);
  k_scatter<<<(N_EDGES + 255) / 256, 256, 0, stream>>>(esrc, edst, cursor, csr, N_EDGES);

  const float invN = 1.0f / (float)N_NODES;
  const float invG = 1.0f / (float)N_GRAPHS;

  // ---- 5 GIN layers ----
  const uint* xin = hb;
  for (int layer = 0; layer < 5; layer++) {
    const ushort* Wl = Wt + (size_t)layer * 128 * 128;
    const float* bl = (layer == 0) ? b1 : bg + (size_t)(layer - 1) * 128;
    const float* gl = (layer == 0) ? g1g : gg + (size_t)(layer - 1) * 128;
    const float* bl2 = (layer == 0) ? g1b : gb + (size_t)(layer - 1) * 128;

    k_agg<<<(N_NODES + 3) / 4, 256, 0, stream>>>(xin, row_ptr, csr, Mb, N_NODES);
    k_gemm_mfma<<<(N_NODES + 127) / 128, 256, 0, stream>>>((const ushort*)Mb, Wl, bl, 2.0f,
                                                           (ushort*)yb, N_NODES);
    hipMemsetAsync(ssum, 0, 128 * sizeof(float), stream);
    hipMemsetAsync(ssq, 0, 128 * sizeof(float), stream);
    k_stats_bf<<<128, 256, 0, stream>>>(yb, N_NODES, ssum, ssq);
    k_bnparams<<<1, 128, 0, stream>>>(ssum, ssq, gl, bl2, Ac, Bc, 128, invN);
    k_norm_relu_bf<<<(N_NODES * 64 + 255) / 256, 256, 0, stream>>>(yb, Ac, Bc, xb, N_NODES * 64);
    xin = xb;
  }

  // ---- readout ----
  hipMemsetAsync(xg, 0, (size_t)N_GRAPHS * 128 * sizeof(float), stream);
  k_readout_bf<<<(N_NODES + 255) / 256, 64, 0, stream>>>(xb, gid, xg, N_NODES);

  // ---- fc1 (128 -> 512) + BN + relu ----
  {
    dim3 grid(8, N_GRAPHS / 32);
    k_gemm<<<grid, 256, 0, stream>>>(xg, 128, N_GRAPHS, 128, fc1W, 512, 0, fc1b, 1.0f, y1, 512);
  }
  hipMemsetAsync(ssum, 0, 512 * sizeof(float), stream);
  hipMemsetAsync(ssq, 0, 512 * sizeof(float), stream);
  k_stats<<<256, 512, 0, stream>>>(y1, N_GRAPHS, 512, ssum, ssq);
  k_bnparams<<<1, 512, 0, stream>>>(ssum, ssq, bn1g, bn1b, Ac, Bc, 512, invG);
  k_norm_relu<<<(N_GRAPHS * 512 / 4 + 255) / 256, 256, 0, stream>>>(y1, Ac, Bc, x1,
                                                                    N_GRAPHS * 512, 511);

  // ---- lin (512 -> 256) + BN + relu ----
  {
    dim3 grid(4, N_GRAPHS / 32);
    k_gemm<<<grid, 256, 0, stream>>>(x1, 512, N_GRAPHS, 512, linW, 256, 0, linb, 1.0f, y2, 256);
  }
  hipMemsetAsync(ssum, 0, 256 * sizeof(float), stream);
  hipMemsetAsync(ssq, 0, 256 * sizeof(float), stream);
  k_stats<<<256, 256, 0, stream>>>(y2, N_GRAPHS, 256, ssum, ssq);
  k_bnparams<<<1, 256, 0, stream>>>(ssum, ssq, lbng, lbnb, Ac, Bc, 256, invG);
  k_norm_relu<<<(N_GRAPHS * 256 / 4 + 255) / 256, 256, 0, stream>>>(y2, Ac, Bc, x2,
                                                                    N_GRAPHS * 256, 255);

  // ---- fc2, only last 204 columns, + sigmoid ----
  {
    dim3 grid((NCLS + 63) / 64, N_GRAPHS / 32);
    k_gemm<<<grid, 256, 0, stream>>>(x2, 256, N_GRAPHS, 256, fc2W, 408, 204, fc2b, 1.0f,
                                     ylog, NCLS);
  }
  {
    int total = N_GRAPHS * NCLS;
    k_sigmoid<<<(total + 255) / 256, 256, 0, stream>>>(ylog, out, total);
  }
}

// Round 3
// 951.425 us; speedup vs baseline: 2.7999x; 1.9139x over previous
//
#include <hip/hip_runtime.h>
#include <hip/hip_bf16.h>
#include <math.h>

#define N_NODES 100000
#define N_EDGES 1600000
#define N_GRAPHS 2048
#define NCLS 204
#define EPS_BN 1e-5f

typedef __attribute__((ext_vector_type(8))) short short8;
typedef __attribute__((ext_vector_type(4))) float f32x4;

__device__ __forceinline__ float bf_lo(uint v) { union { uint i; float f; } c; c.i = v << 16; return c.f; }
__device__ __forceinline__ float bf_hi(uint v) { union { uint i; float f; } c; c.i = v & 0xffff0000u; return c.f; }
__device__ __forceinline__ ushort f2bf(float v) {
  __hip_bfloat16 b = __float2bfloat16(v);
  return *reinterpret_cast<ushort*>(&b);
}
__device__ __forceinline__ uint pack2(float a, float b) {
  return (uint)f2bf(a) | ((uint)f2bf(b) << 16);
}

// ---------------- CSR build ----------------
__global__ void k_degree(const int* __restrict__ dst, int* __restrict__ deg, int E) {
  int i = blockIdx.x * blockDim.x + threadIdx.x;
  if (i < E) atomicAdd(&deg[dst[i]], 1);
}

// phase A: per-block (1024 elems) sums
__global__ __launch_bounds__(256) void k_scan_part(const int* __restrict__ deg,
                                                   int* __restrict__ part, int n) {
  __shared__ int red[256];
  int t = threadIdx.x;
  int base = blockIdx.x * 1024 + t * 4;
  int s = 0;
  if (base + 4 <= n) {
    int4 v = *reinterpret_cast<const int4*>(deg + base);
    s = v.x + v.y + v.z + v.w;
  } else {
    for (int k = 0; k < 4; k++) if (base + k < n) s += deg[base + k];
  }
  red[t] = s;
  __syncthreads();
  for (int d = 128; d > 0; d >>= 1) {
    if (t < d) red[t] += red[t + d];
    __syncthreads();
  }
  if (t == 0) part[blockIdx.x] = red[0];
}

// phase B: exclusive scan of up to 128 partials (in-place)
__global__ __launch_bounds__(128) void k_scan_off(int* __restrict__ part, int nb) {
  __shared__ int sh[128];
  int t = threadIdx.x;
  sh[t] = (t < nb) ? part[t] : 0;
  __syncthreads();
  for (int d = 1; d < 128; d <<= 1) {
    int v = (t >= d) ? sh[t - d] : 0;
    __syncthreads();
    sh[t] += v;
    __syncthreads();
  }
  if (t < nb) part[t] = (t == 0) ? 0 : sh[t - 1];
}

// phase C: write row_ptr
__global__ __launch_bounds__(256) void k_scan_write(const int* __restrict__ deg,
                                                    const int* __restrict__ part,
                                                    int* __restrict__ row_ptr, int n) {
  __shared__ int red[256];
  int t = threadIdx.x;
  int base = blockIdx.x * 1024 + t * 4;
  int v[4];
  int s = 0;
  for (int k = 0; k < 4; k++) {
    v[k] = (base + k < n) ? deg[base + k] : 0;
    s += v[k];
  }
  red[t] = s;
  __syncthreads();
  for (int d = 1; d < 256; d <<= 1) {
    int x = (t >= d) ? red[t - d] : 0;
    __syncthreads();
    red[t] += x;
    __syncthreads();
  }
  int run = part[blockIdx.x] + ((t == 0) ? 0 : red[t - 1]);
  for (int k = 0; k < 4; k++) {
    if (base + k < n) row_ptr[base + k] = run;
    run += v[k];
  }
  if (blockIdx.x == gridDim.x - 1 && t == 255) row_ptr[n] = run;
}

__global__ void k_scatter(const int* __restrict__ src, const int* __restrict__ dst,
                          int* __restrict__ cursor, int* __restrict__ csr_src, int E) {
  int i = blockIdx.x * blockDim.x + threadIdx.x;
  if (i < E) {
    int p = atomicAdd(&cursor[dst[i]], 1);
    csr_src[p] = src[i];
  }
}

// ---------------- conversions / weight prep ----------------
__global__ void k_conv_h(const float* __restrict__ h, uint* __restrict__ hb, int nNodes) {
  int i = blockIdx.x * blockDim.x + threadIdx.x;
  if (i < nNodes * 64) {
    int n = i >> 6, cp = i & 63;
    int c = cp * 2;
    float a = (c < 78) ? h[(size_t)n * 78 + c] : 0.0f;
    float b = (c + 1 < 78) ? h[(size_t)n * 78 + c + 1] : 0.0f;
    hb[i] = pack2(a, b);
  }
}

__global__ void k_prep_wt(const float* __restrict__ W, ushort* __restrict__ Wt, int K) {
  int i = blockIdx.x * blockDim.x + threadIdx.x;
  if (i < 128 * 128) {
    int n = i >> 7, k = i & 127;
    float v = (k < K) ? W[(size_t)k * 128 + n] : 0.0f;
    Wt[i] = f2bf(v);
  }
}

// ---------------- GIN aggregation, fused with prev layer's BN+ReLU ----------------
// M = 2*f(y_self) + sum f(y_src);  f(v) = NRM ? relu(v*A+B) : v
template <bool NRM>
__global__ __launch_bounds__(256) void k_agg_f(const uint* __restrict__ y,
                                               const int* __restrict__ row_ptr,
                                               const int* __restrict__ csr,
                                               const float* __restrict__ Ac,
                                               const float* __restrict__ Bc,
                                               uint* __restrict__ M, int nNodes) {
  int n = blockIdx.x * 4 + (threadIdx.x >> 6);
  if (n >= nNodes) return;
  int l = threadIdx.x & 63;
  float A0 = 1.f, B0 = 0.f, A1 = 1.f, B1 = 0.f;
  if (NRM) { A0 = Ac[2 * l]; B0 = Bc[2 * l]; A1 = Ac[2 * l + 1]; B1 = Bc[2 * l + 1]; }

  auto flo = [&](uint v) { float x = bf_lo(v); return NRM ? fmaxf(x * A0 + B0, 0.f) : x; };
  auto fhi = [&](uint v) { float x = bf_hi(v); return NRM ? fmaxf(x * A1 + B1, 0.f) : x; };

  uint self = y[(size_t)n * 64 + l];
  float a0 = 2.0f * flo(self);
  float a1 = 2.0f * fhi(self);
  int s = row_ptr[n], e = row_ptr[n + 1];
  int i = s;
  for (; i + 4 <= e; i += 4) {
    int s0 = csr[i], s1 = csr[i + 1], s2 = csr[i + 2], s3 = csr[i + 3];
    uint v0 = y[(size_t)s0 * 64 + l];
    uint v1 = y[(size_t)s1 * 64 + l];
    uint v2 = y[(size_t)s2 * 64 + l];
    uint v3 = y[(size_t)s3 * 64 + l];
    a0 += flo(v0) + flo(v1) + flo(v2) + flo(v3);
    a1 += fhi(v0) + fhi(v1) + fhi(v2) + fhi(v3);
  }
  for (; i < e; i++) {
    uint v = y[(size_t)csr[i] * 64 + l];
    a0 += flo(v);
    a1 += fhi(v);
  }
  M[(size_t)n * 64 + l] = pack2(a0, a1);
}

// ---------------- MFMA GEMM + fused BN stats ----------------
#define SWZ(row, boff) ((boff) ^ (((row) & 7) << 4))
__global__ __launch_bounds__(256) void k_gemm_mfma(const ushort* __restrict__ A,
                                                   const ushort* __restrict__ Wt,
                                                   const float* __restrict__ bias, float bscale,
                                                   ushort* __restrict__ Y, int Mrows,
                                                   float* __restrict__ gsum,
                                                   float* __restrict__ gsq) {
  __shared__ ushort As[128 * 128];
  __shared__ ushort Bs[128 * 128];
  __shared__ float sred[4][128], qred[4][128];
  int t = threadIdx.x;
  int r0 = blockIdx.x * 128;
  char* Ab = (char*)As;
  char* Bb = (char*)Bs;

  for (int it = 0; it < 8; it++) {
    int e = it * 256 + t;
    int row = e >> 4, seg = e & 15;
    uint4 va = make_uint4(0, 0, 0, 0);
    int gr = r0 + row;
    if (gr < Mrows) va = *reinterpret_cast<const uint4*>(A + (size_t)gr * 128 + seg * 8);
    *reinterpret_cast<uint4*>(Ab + row * 256 + SWZ(row, seg * 16)) = va;
    uint4 vb = *reinterpret_cast<const uint4*>(Wt + (size_t)row * 128 + seg * 8);
    *reinterpret_cast<uint4*>(Bb + row * 256 + SWZ(row, seg * 16)) = vb;
  }
  __syncthreads();

  int wi = t >> 6;
  int l = t & 63;
  int lr = l & 15;
  int kp = l >> 4;

  f32x4 acc[2][8];
#pragma unroll
  for (int mi = 0; mi < 2; mi++)
#pragma unroll
    for (int ni = 0; ni < 8; ni++) acc[mi][ni] = (f32x4){0.f, 0.f, 0.f, 0.f};

#pragma unroll
  for (int ki = 0; ki < 4; ki++) {
    short8 a[2], b[8];
#pragma unroll
    for (int mi = 0; mi < 2; mi++) {
      int row = wi * 32 + mi * 16 + lr;
      a[mi] = *reinterpret_cast<const short8*>(Ab + row * 256 + SWZ(row, ki * 64 + kp * 16));
    }
#pragma unroll
    for (int ni = 0; ni < 8; ni++) {
      int row = ni * 16 + lr;
      b[ni] = *reinterpret_cast<const short8*>(Bb + row * 256 + SWZ(row, ki * 64 + kp * 16));
    }
#pragma unroll
    for (int mi = 0; mi < 2; mi++)
#pragma unroll
      for (int ni = 0; ni < 8; ni++)
        acc[mi][ni] = __builtin_amdgcn_mfma_f32_16x16x32_bf16(a[mi], b[ni], acc[mi][ni], 0, 0, 0);
  }

  float s_part[8], q_part[8];
#pragma unroll
  for (int ni = 0; ni < 8; ni++) { s_part[ni] = 0.f; q_part[ni] = 0.f; }

#pragma unroll
  for (int mi = 0; mi < 2; mi++) {
    int rbase = r0 + wi * 32 + mi * 16 + kp * 4;
#pragma unroll
    for (int ni = 0; ni < 8; ni++) {
      int col = ni * 16 + lr;
      float bb = bscale * bias[col];
#pragma unroll
      for (int j = 0; j < 4; j++) {
        int r = rbase + j;
        if (r < Mrows) {
          float yv = acc[mi][ni][j] + bb;
          Y[(size_t)r * 128 + col] = f2bf(yv);
          s_part[ni] += yv;
          q_part[ni] += yv * yv;
        }
      }
    }
  }

#pragma unroll
  for (int ni = 0; ni < 8; ni++) {
    s_part[ni] += __shfl_xor(s_part[ni], 16, 64);
    s_part[ni] += __shfl_xor(s_part[ni], 32, 64);
    q_part[ni] += __shfl_xor(q_part[ni], 16, 64);
    q_part[ni] += __shfl_xor(q_part[ni], 32, 64);
  }
  if (kp == 0) {
#pragma unroll
    for (int ni = 0; ni < 8; ni++) {
      sred[wi][ni * 16 + lr] = s_part[ni];
      qred[wi][ni * 16 + lr] = q_part[ni];
    }
  }
  __syncthreads();
  if (t < 128) {
    float S = sred[0][t] + sred[1][t] + sred[2][t] + sred[3][t];
    float Q = qred[0][t] + qred[1][t] + qred[2][t] + qred[3][t];
    atomicAdd(&gsum[t], S);
    atomicAdd(&gsq[t], Q);
  }
}

__global__ void k_bnparams(const float* __restrict__ sum, const float* __restrict__ sumsq,
                           const float* __restrict__ gamma, const float* __restrict__ beta,
                           float* __restrict__ Ac, float* __restrict__ Bc,
                           int C, float invM) {
  int c = blockIdx.x * blockDim.x + threadIdx.x;
  if (c < C) {
    float mu = sum[c] * invM;
    float var = sumsq[c] * invM - mu * mu;
    float rs = rsqrtf(var + EPS_BN);
    float a = gamma[c] * rs;
    Ac[c] = a;
    Bc[c] = beta[c] - mu * a;
  }
}

// ---------------- graph readout: xg[g] = sum relu(y*A+B), sorted gids ----------------
__global__ __launch_bounds__(64) void k_readout(const uint* __restrict__ y,
                                                const int* __restrict__ gid,
                                                const float* __restrict__ Ac,
                                                const float* __restrict__ Bc,
                                                float* __restrict__ xg, int nNodes) {
  int l = threadIdx.x;
  int n0 = blockIdx.x * 64;
  int n1 = min(n0 + 64, nNodes);
  if (n0 >= nNodes) return;
  float A0 = Ac[2 * l], B0 = Bc[2 * l], A1 = Ac[2 * l + 1], B1 = Bc[2 * l + 1];
  float a0 = 0, a1 = 0;
  int cur = gid[n0];
  for (int n = n0; n < n1; n++) {
    int g = gid[n];
    if (g != cur) {
      atomicAdd(&xg[(size_t)cur * 128 + 2 * l], a0);
      atomicAdd(&xg[(size_t)cur * 128 + 2 * l + 1], a1);
      a0 = 0; a1 = 0; cur = g;
    }
    uint v = y[(size_t)n * 64 + l];
    a0 += fmaxf(bf_lo(v) * A0 + B0, 0.f);
    a1 += fmaxf(bf_hi(v) * A1 + B1, 0.f);
  }
  atomicAdd(&xg[(size_t)cur * 128 + 2 * l], a0);
  atomicAdd(&xg[(size_t)cur * 128 + 2 * l + 1], a1);
}

// ---------------- generic fp32 GEMM for MLP head (act: 0=none, 1=sigmoid) ----------------
#define KTILE 128
__global__ __launch_bounds__(256) void k_gemm(const float* __restrict__ A, int lda,
                                              int Mrows, int K,
                                              const float* __restrict__ W, int wld,
                                              int col_off,
                                              const float* __restrict__ bias,
                                              float* __restrict__ Y, int ncols, int act) {
  __shared__ float At[KTILE][36];
  __shared__ float Ws[KTILE][64];
  int t = threadIdx.x;
  int tx = t & 31;
  int ty = t >> 5;
  int r0 = blockIdx.y * 32;
  int c0 = blockIdx.x * 64;
  float acc[4][2] = {};

  for (int k0 = 0; k0 < K; k0 += KTILE) {
    int kt = min(KTILE, K - k0);
    for (int e = t; e < 32 * kt; e += 256) {
      int r = e / kt, k = e - r * kt;
      int gr = r0 + r;
      At[k][r] = (gr < Mrows) ? A[(size_t)gr * lda + k0 + k] : 0.0f;
    }
    for (int e = t; e < kt * 64; e += 256) {
      int k = e >> 6, c = e & 63;
      int gc = c0 + c;
      Ws[k][c] = (gc < ncols) ? W[(size_t)(k0 + k) * wld + col_off + gc] : 0.0f;
    }
    __syncthreads();
    for (int k = 0; k < kt; k++) {
      float4 a = *reinterpret_cast<const float4*>(&At[k][ty * 4]);
      float2 w = *reinterpret_cast<const float2*>(&Ws[k][tx * 2]);
      acc[0][0] += a.x * w.x; acc[0][1] += a.x * w.y;
      acc[1][0] += a.y * w.x; acc[1][1] += a.y * w.y;
      acc[2][0] += a.z * w.x; acc[2][1] += a.z * w.y;
      acc[3][0] += a.w * w.x; acc[3][1] += a.w * w.y;
    }
    __syncthreads();
  }

  for (int i = 0; i < 4; i++) {
    int r = r0 + ty * 4 + i;
    if (r >= Mrows) continue;
    for (int j = 0; j < 2; j++) {
      int c = c0 + tx * 2 + j;
      if (c < ncols) {
        float v = acc[i][j] + bias[col_off + c];
        if (act == 1) v = 1.0f / (1.0f + expf(-v));
        Y[(size_t)r * ncols + c] = v;
      }
    }
  }
}

__global__ void k_stats(const float* __restrict__ Y, int Mrows, int C,
                        float* __restrict__ sum, float* __restrict__ sumsq) {
  int c = threadIdx.x;
  float s = 0.0f, q = 0.0f;
  for (int r = blockIdx.x; r < Mrows; r += gridDim.x) {
    float v = Y[(size_t)r * C + c];
    s += v;
    q += v * v;
  }
  atomicAdd(&sum[c], s);
  atomicAdd(&sumsq[c], q);
}

__global__ void k_norm_relu(const float* __restrict__ Y, const float* __restrict__ Ac,
                            const float* __restrict__ Bc, float* __restrict__ X,
                            int total, int cmask) {
  int i = (blockIdx.x * blockDim.x + threadIdx.x) * 4;
  if (i < total) {
    float4 v = *reinterpret_cast<const float4*>(&Y[i]);
    int c = i & cmask;
    v.x = fmaxf(v.x * Ac[c] + Bc[c], 0.0f);
    v.y = fmaxf(v.y * Ac[c + 1] + Bc[c + 1], 0.0f);
    v.z = fmaxf(v.z * Ac[c + 2] + Bc[c + 2], 0.0f);
    v.w = fmaxf(v.w * Ac[c + 3] + Bc[c + 3], 0.0f);
    *reinterpret_cast<float4*>(&X[i]) = v;
  }
}

extern "C" void kernel_launch(void* const* d_in, const int* in_sizes, int n_in,
                              void* d_out, int out_size, void* d_ws, size_t ws_size,
                              hipStream_t stream) {
  const float* h    = (const float*)d_in[0];
  const int*   esrc = (const int*)d_in[1];
  const int*   edst = (const int*)d_in[2];
  const int*   gid  = (const int*)d_in[3];
  const float* W1   = (const float*)d_in[4];
  const float* b1   = (const float*)d_in[5];
  const float* g1g  = (const float*)d_in[6];
  const float* g1b  = (const float*)d_in[7];
  const float* Wg   = (const float*)d_in[8];
  const float* bg   = (const float*)d_in[9];
  const float* gg   = (const float*)d_in[10];
  const float* gb   = (const float*)d_in[11];
  const float* fc1W = (const float*)d_in[12];
  const float* fc1b = (const float*)d_in[13];
  const float* bn1g = (const float*)d_in[14];
  const float* bn1b = (const float*)d_in[15];
  const float* linW = (const float*)d_in[16];
  const float* linb = (const float*)d_in[17];
  const float* lbng = (const float*)d_in[18];
  const float* lbnb = (const float*)d_in[19];
  const float* fc2W = (const float*)d_in[20];
  const float* fc2b = (const float*)d_in[21];
  float* out = (float*)d_out;

  char* p = (char*)d_ws;
  auto alloc = [&](size_t bytes) {
    char* q = p;
    p += (bytes + 255) & ~(size_t)255;
    return q;
  };
  int* row_ptr = (int*)alloc((N_NODES + 1) * sizeof(int));
  int* cursor  = (int*)alloc(N_NODES * sizeof(int));   // degree, then scatter cursor
  int* part    = (int*)alloc(128 * sizeof(int));
  int* csr     = (int*)alloc(N_EDGES * sizeof(int));
  uint* hb     = (uint*)alloc((size_t)N_NODES * 64 * sizeof(uint));
  uint* Mb     = (uint*)alloc((size_t)N_NODES * 64 * sizeof(uint));
  uint* yb     = (uint*)alloc((size_t)N_NODES * 64 * sizeof(uint));
  ushort* Wt   = (ushort*)alloc(5 * 128 * 128 * sizeof(ushort));
  float* ssum  = (float*)alloc(512 * sizeof(float));
  float* ssq   = (float*)alloc(512 * sizeof(float));
  float* Ac    = (float*)alloc(512 * sizeof(float));
  float* Bc    = (float*)alloc(512 * sizeof(float));
  float* xg    = (float*)alloc((size_t)N_GRAPHS * 128 * sizeof(float));
  float* y1    = (float*)alloc((size_t)N_GRAPHS * 512 * sizeof(float));
  float* x1    = (float*)alloc((size_t)N_GRAPHS * 512 * sizeof(float));
  float* y2    = (float*)alloc((size_t)N_GRAPHS * 256 * sizeof(float));
  float* x2    = (float*)alloc((size_t)N_GRAPHS * 256 * sizeof(float));

  // ---- prep: conversions + CSR build ----
  k_conv_h<<<(N_NODES * 64 + 255) / 256, 256, 0, stream>>>(h, hb, N_NODES);
  k_prep_wt<<<64, 256, 0, stream>>>(W1, Wt, 78);
  for (int l = 0; l < 4; l++)
    k_prep_wt<<<64, 256, 0, stream>>>(Wg + (size_t)l * 128 * 128, Wt + (size_t)(l + 1) * 128 * 128, 128);

  const int NB = (N_NODES + 1023) / 1024;  // 98
  hipMemsetAsync(cursor, 0, N_NODES * sizeof(int), stream);
  k_degree<<<(N_EDGES + 255) / 256, 256, 0, stream>>>(edst, cursor, N_EDGES);
  k_scan_part<<<NB, 256, 0, stream>>>(cursor, part, N_NODES);
  k_scan_off<<<1, 128, 0, stream>>>(part, NB);
  k_scan_write<<<NB, 256, 0, stream>>>(cursor, part, row_ptr, N_NODES);
  hipMemcpyAsync(cursor, row_ptr, N_NODES * sizeof(int), hipMemcpyDeviceToDevice, stream);
  k_scatter<<<(N_EDGES + 255) / 256, 256, 0, stream>>>(esrc, edst, cursor, csr, N_EDGES);

  const float invN = 1.0f / (float)N_NODES;
  const float invG = 1.0f / (float)N_GRAPHS;

  // ---- 5 GIN layers: agg(+prev BN/ReLU) -> MFMA GEMM(+stats) -> bnparams ----
  for (int layer = 0; layer < 5; layer++) {
    const ushort* Wl = Wt + (size_t)layer * 128 * 128;
    const float* bl  = (layer == 0) ? b1 : bg + (size_t)(layer - 1) * 128;
    const float* gl  = (layer == 0) ? g1g : gg + (size_t)(layer - 1) * 128;
    const float* bl2 = (layer == 0) ? g1b : gb + (size_t)(layer - 1) * 128;

    if (layer == 0)
      k_agg_f<false><<<(N_NODES + 3) / 4, 256, 0, stream>>>(hb, row_ptr, csr, nullptr, nullptr,
                                                            Mb, N_NODES);
    else
      k_agg_f<true><<<(N_NODES + 3) / 4, 256, 0, stream>>>(yb, row_ptr, csr, Ac, Bc,
                                                           Mb, N_NODES);
    hipMemsetAsync(ssum, 0, 128 * sizeof(float), stream);
    hipMemsetAsync(ssq, 0, 128 * sizeof(float), stream);
    k_gemm_mfma<<<(N_NODES + 127) / 128, 256, 0, stream>>>((const ushort*)Mb, Wl, bl, 2.0f,
                                                           (ushort*)yb, N_NODES, ssum, ssq);
    k_bnparams<<<1, 128, 0, stream>>>(ssum, ssq, gl, bl2, Ac, Bc, 128, invN);
  }

  // ---- readout (applies layer-5 BN+ReLU inline) ----
  hipMemsetAsync(xg, 0, (size_t)N_GRAPHS * 128 * sizeof(float), stream);
  k_readout<<<(N_NODES + 63) / 64, 64, 0, stream>>>(yb, gid, Ac, Bc, xg, N_NODES);

  // ---- fc1 (128 -> 512) + BN + relu ----
  {
    dim3 grid(8, N_GRAPHS / 32);
    k_gemm<<<grid, 256, 0, stream>>>(xg, 128, N_GRAPHS, 128, fc1W, 512, 0, fc1b, y1, 512, 0);
  }
  hipMemsetAsync(ssum, 0, 512 * sizeof(float), stream);
  hipMemsetAsync(ssq, 0, 512 * sizeof(float), stream);
  k_stats<<<256, 512, 0, stream>>>(y1, N_GRAPHS, 512, ssum, ssq);
  k_bnparams<<<1, 512, 0, stream>>>(ssum, ssq, bn1g, bn1b, Ac, Bc, 512, invG);
  k_norm_relu<<<(N_GRAPHS * 512 / 4 + 255) / 256, 256, 0, stream>>>(y1, Ac, Bc, x1,
                                                                    N_GRAPHS * 512, 511);

  // ---- lin (512 -> 256) + BN + relu ----
  {
    dim3 grid(4, N_GRAPHS / 32);
    k_gemm<<<grid, 256, 0, stream>>>(x1, 512, N_GRAPHS, 512, linW, 256, 0, linb, y2, 256, 0);
  }
  hipMemsetAsync(ssum, 0, 256 * sizeof(float), stream);
  hipMemsetAsync(ssq, 0, 256 * sizeof(float), stream);
  k_stats<<<256, 256, 0, stream>>>(y2, N_GRAPHS, 256, ssum, ssq);
  k_bnparams<<<1, 256, 0, stream>>>(ssum, ssq, lbng, lbnb, Ac, Bc, 256, invG);
  k_norm_relu<<<(N_GRAPHS * 256 / 4 + 255) / 256, 256, 0, stream>>>(y2, Ac, Bc, x2,
                                                                    N_GRAPHS * 256, 255);

  // ---- fc2: last 204 columns, sigmoid fused, write d_out ----
  {
    dim3 grid((NCLS + 63) / 64, N_GRAPHS / 32);
    k_gemm<<<grid, 256, 0, stream>>>(x2, 256, N_GRAPHS, 256, fc2W, 408, 204, fc2b, out,
                                     NCLS, 1);
  }
}

// Round 4
// 835.310 us; speedup vs baseline: 3.1891x; 1.1390x over previous
//
#include <hip/hip_runtime.h>
#include <hip/hip_bf16.h>
#include <math.h>

#define N_NODES 100000
#define N_EDGES 1600000
#define N_GRAPHS 2048
#define NCLS 204
#define EPS_BN 1e-5f
#define NBUCK ((N_NODES + 255) / 256)   // 391
#define BIN_CHUNK 8192

typedef __attribute__((ext_vector_type(8))) short short8;
typedef __attribute__((ext_vector_type(4))) float f32x4;

__device__ __forceinline__ float bf_lo(uint v) { union { uint i; float f; } c; c.i = v << 16; return c.f; }
__device__ __forceinline__ float bf_hi(uint v) { union { uint i; float f; } c; c.i = v & 0xffff0000u; return c.f; }
__device__ __forceinline__ ushort f2bf(float v) {
  __hip_bfloat16 b = __float2bfloat16(v);
  return *reinterpret_cast<ushort*>(&b);
}
__device__ __forceinline__ uint pack2(float a, float b) {
  return (uint)f2bf(a) | ((uint)f2bf(b) << 16);
}

// ---------------- CSR build ----------------
__global__ void k_degree(const int* __restrict__ dst, int* __restrict__ deg, int E) {
  int i = blockIdx.x * blockDim.x + threadIdx.x;
  if (i < E) atomicAdd(&deg[dst[i]], 1);
}

__global__ __launch_bounds__(256) void k_scan_part(const int* __restrict__ deg,
                                                   int* __restrict__ part, int n) {
  __shared__ int red[256];
  int t = threadIdx.x;
  int base = blockIdx.x * 1024 + t * 4;
  int s = 0;
  if (base + 4 <= n) {
    int4 v = *reinterpret_cast<const int4*>(deg + base);
    s = v.x + v.y + v.z + v.w;
  } else {
    for (int k = 0; k < 4; k++) if (base + k < n) s += deg[base + k];
  }
  red[t] = s;
  __syncthreads();
  for (int d = 128; d > 0; d >>= 1) {
    if (t < d) red[t] += red[t + d];
    __syncthreads();
  }
  if (t == 0) part[blockIdx.x] = red[0];
}

__global__ __launch_bounds__(128) void k_scan_off(int* __restrict__ part, int nb) {
  __shared__ int sh[128];
  int t = threadIdx.x;
  sh[t] = (t < nb) ? part[t] : 0;
  __syncthreads();
  for (int d = 1; d < 128; d <<= 1) {
    int v = (t >= d) ? sh[t - d] : 0;
    __syncthreads();
    sh[t] += v;
    __syncthreads();
  }
  if (t < nb) part[t] = (t == 0) ? 0 : sh[t - 1];
}

__global__ __launch_bounds__(256) void k_scan_write(const int* __restrict__ deg,
                                                    const int* __restrict__ part,
                                                    int* __restrict__ row_ptr, int n) {
  __shared__ int red[256];
  int t = threadIdx.x;
  int base = blockIdx.x * 1024 + t * 4;
  int v[4];
  int s = 0;
  for (int k = 0; k < 4; k++) {
    v[k] = (base + k < n) ? deg[base + k] : 0;
    s += v[k];
  }
  red[t] = s;
  __syncthreads();
  for (int d = 1; d < 256; d <<= 1) {
    int x = (t >= d) ? red[t - d] : 0;
    __syncthreads();
    red[t] += x;
    __syncthreads();
  }
  int run = part[blockIdx.x] + ((t == 0) ? 0 : red[t - 1]);
  for (int k = 0; k < 4; k++) {
    if (base + k < n) row_ptr[base + k] = run;
    run += v[k];
  }
  if (blockIdx.x == gridDim.x - 1 && t == 255) row_ptr[n] = run;
}

// bucket cursors init: cursor[b] = row_ptr[b*256]
__global__ void k_init_cursor(const int* __restrict__ row_ptr, int* __restrict__ cursor) {
  int b = blockIdx.x * blockDim.x + threadIdx.x;
  if (b < NBUCK) cursor[b] = row_ptr[b * 256];
}

// phase 1: bin edges by dst>>8 into bucket-contiguous staging (uint2 = src,dst)
__global__ __launch_bounds__(256) void k_bin(const int* __restrict__ src,
                                             const int* __restrict__ dst,
                                             int* __restrict__ cursor,
                                             uint2* __restrict__ staging, int E) {
  __shared__ int hist[NBUCK];
  __shared__ int base_s[NBUCK];
  int t = threadIdx.x;
  int e0 = blockIdx.x * BIN_CHUNK;
  for (int b = t; b < NBUCK; b += 256) hist[b] = 0;
  __syncthreads();
  for (int e = e0 + t; e < min(e0 + BIN_CHUNK, E); e += 256)
    atomicAdd(&hist[dst[e] >> 8], 1);
  __syncthreads();
  for (int b = t; b < NBUCK; b += 256) {
    int hh = hist[b];
    if (hh > 0) base_s[b] = atomicAdd(&cursor[b], hh);
    hist[b] = 0;
  }
  __syncthreads();
  for (int e = e0 + t; e < min(e0 + BIN_CHUNK, E); e += 256) {
    int d = dst[e];
    int b = d >> 8;
    int r = atomicAdd(&hist[b], 1);
    staging[base_s[b] + r] = make_uint2((uint)src[e], (uint)d);
  }
}

// phase 2: one block per bucket; place srcs at per-node positions (LDS cursors)
__global__ __launch_bounds__(256) void k_place(const uint2* __restrict__ staging,
                                               const int* __restrict__ row_ptr,
                                               int* __restrict__ csr, int nNodes) {
  __shared__ int cur[256];
  int t = threadIdx.x;
  int n0 = blockIdx.x * 256;
  int nend = min(n0 + 256, nNodes);
  if (n0 + t < nend) cur[t] = row_ptr[n0 + t];
  __syncthreads();
  int s = row_ptr[n0];
  int e = row_ptr[nend];
  for (int i = s + t; i < e; i += 256) {
    uint2 ed = staging[i];
    int pos = atomicAdd(&cur[ed.y - n0], 1);
    csr[pos] = (int)ed.x;
  }
}

// ---------------- conversions / weight prep ----------------
__global__ void k_conv_h(const float* __restrict__ h, uint* __restrict__ hb, int nNodes) {
  int i = blockIdx.x * blockDim.x + threadIdx.x;
  if (i < nNodes * 64) {
    int n = i >> 6, cp = i & 63;
    int c = cp * 2;
    float a = (c < 78) ? h[(size_t)n * 78 + c] : 0.0f;
    float b = (c + 1 < 78) ? h[(size_t)n * 78 + c + 1] : 0.0f;
    hb[i] = pack2(a, b);
  }
}

__global__ void k_prep_wt(const float* __restrict__ W, ushort* __restrict__ Wt, int K) {
  int i = blockIdx.x * blockDim.x + threadIdx.x;
  if (i < 128 * 128) {
    int n = i >> 7, k = i & 127;
    float v = (k < K) ? W[(size_t)k * 128 + n] : 0.0f;
    Wt[i] = f2bf(v);
  }
}

// ---------------- GIN aggregation, fused with prev layer's BN+ReLU ----------------
// M = 2*f(y_self) + sum f(y_src);  f(v) = NRM ? relu(v*A+B) : v
template <bool NRM>
__global__ __launch_bounds__(256) void k_agg_f(const uint* __restrict__ y,
                                               const int* __restrict__ row_ptr,
                                               const int* __restrict__ csr,
                                               const float* __restrict__ Ac,
                                               const float* __restrict__ Bc,
                                               uint* __restrict__ M, int nNodes) {
  int n = blockIdx.x * 4 + (threadIdx.x >> 6);
  if (n >= nNodes) return;
  int l = threadIdx.x & 63;
  float A0 = 1.f, B0 = 0.f, A1 = 1.f, B1 = 0.f;
  if (NRM) { A0 = Ac[2 * l]; B0 = Bc[2 * l]; A1 = Ac[2 * l + 1]; B1 = Bc[2 * l + 1]; }

  auto flo = [&](uint v) { float x = bf_lo(v); return NRM ? fmaxf(x * A0 + B0, 0.f) : x; };
  auto fhi = [&](uint v) { float x = bf_hi(v); return NRM ? fmaxf(x * A1 + B1, 0.f) : x; };

  uint self = y[(size_t)n * 64 + l];
  float a0 = 2.0f * flo(self);
  float a1 = 2.0f * fhi(self);
  int s = row_ptr[n], e = row_ptr[n + 1];

  for (int base = s; base < e; base += 64) {
    int cnt = e - base;
    if (cnt > 64) cnt = 64;
    int myidx = (base + l < e) ? csr[base + l] : 0;
    int j = 0;
    for (; j + 4 <= cnt; j += 4) {
      int i0 = __shfl(myidx, j);
      int i1 = __shfl(myidx, j + 1);
      int i2 = __shfl(myidx, j + 2);
      int i3 = __shfl(myidx, j + 3);
      uint v0 = y[(size_t)i0 * 64 + l];
      uint v1 = y[(size_t)i1 * 64 + l];
      uint v2 = y[(size_t)i2 * 64 + l];
      uint v3 = y[(size_t)i3 * 64 + l];
      a0 += flo(v0) + flo(v1) + flo(v2) + flo(v3);
      a1 += fhi(v0) + fhi(v1) + fhi(v2) + fhi(v3);
    }
    for (; j < cnt; j++) {
      int i0 = __shfl(myidx, j);
      uint v = y[(size_t)i0 * 64 + l];
      a0 += flo(v);
      a1 += fhi(v);
    }
  }
  M[(size_t)n * 64 + l] = pack2(a0, a1);
}

// ---------------- MFMA GEMM + fused BN stats ----------------
#define SWZ(row, boff) ((boff) ^ (((row) & 7) << 4))
__global__ __launch_bounds__(256) void k_gemm_mfma(const ushort* __restrict__ A,
                                                   const ushort* __restrict__ Wt,
                                                   const float* __restrict__ bias, float bscale,
                                                   ushort* __restrict__ Y, int Mrows,
                                                   float* __restrict__ gsum,
                                                   float* __restrict__ gsq) {
  __shared__ ushort As[128 * 128];
  __shared__ ushort Bs[128 * 128];
  __shared__ float sred[4][128], qred[4][128];
  int t = threadIdx.x;
  int r0 = blockIdx.x * 128;
  char* Ab = (char*)As;
  char* Bb = (char*)Bs;

  for (int it = 0; it < 8; it++) {
    int e = it * 256 + t;
    int row = e >> 4, seg = e & 15;
    uint4 va = make_uint4(0, 0, 0, 0);
    int gr = r0 + row;
    if (gr < Mrows) va = *reinterpret_cast<const uint4*>(A + (size_t)gr * 128 + seg * 8);
    *reinterpret_cast<uint4*>(Ab + row * 256 + SWZ(row, seg * 16)) = va;
    uint4 vb = *reinterpret_cast<const uint4*>(Wt + (size_t)row * 128 + seg * 8);
    *reinterpret_cast<uint4*>(Bb + row * 256 + SWZ(row, seg * 16)) = vb;
  }
  __syncthreads();

  int wi = t >> 6;
  int l = t & 63;
  int lr = l & 15;
  int kp = l >> 4;

  f32x4 acc[2][8];
#pragma unroll
  for (int mi = 0; mi < 2; mi++)
#pragma unroll
    for (int ni = 0; ni < 8; ni++) acc[mi][ni] = (f32x4){0.f, 0.f, 0.f, 0.f};

#pragma unroll
  for (int ki = 0; ki < 4; ki++) {
    short8 a[2], b[8];
#pragma unroll
    for (int mi = 0; mi < 2; mi++) {
      int row = wi * 32 + mi * 16 + lr;
      a[mi] = *reinterpret_cast<const short8*>(Ab + row * 256 + SWZ(row, ki * 64 + kp * 16));
    }
#pragma unroll
    for (int ni = 0; ni < 8; ni++) {
      int row = ni * 16 + lr;
      b[ni] = *reinterpret_cast<const short8*>(Bb + row * 256 + SWZ(row, ki * 64 + kp * 16));
    }
#pragma unroll
    for (int mi = 0; mi < 2; mi++)
#pragma unroll
      for (int ni = 0; ni < 8; ni++)
        acc[mi][ni] = __builtin_amdgcn_mfma_f32_16x16x32_bf16(a[mi], b[ni], acc[mi][ni], 0, 0, 0);
  }

  float s_part[8], q_part[8];
#pragma unroll
  for (int ni = 0; ni < 8; ni++) { s_part[ni] = 0.f; q_part[ni] = 0.f; }

#pragma unroll
  for (int mi = 0; mi < 2; mi++) {
    int rbase = r0 + wi * 32 + mi * 16 + kp * 4;
#pragma unroll
    for (int ni = 0; ni < 8; ni++) {
      int col = ni * 16 + lr;
      float bb = bscale * bias[col];
#pragma unroll
      for (int j = 0; j < 4; j++) {
        int r = rbase + j;
        if (r < Mrows) {
          float yv = acc[mi][ni][j] + bb;
          Y[(size_t)r * 128 + col] = f2bf(yv);
          s_part[ni] += yv;
          q_part[ni] += yv * yv;
        }
      }
    }
  }

#pragma unroll
  for (int ni = 0; ni < 8; ni++) {
    s_part[ni] += __shfl_xor(s_part[ni], 16, 64);
    s_part[ni] += __shfl_xor(s_part[ni], 32, 64);
    q_part[ni] += __shfl_xor(q_part[ni], 16, 64);
    q_part[ni] += __shfl_xor(q_part[ni], 32, 64);
  }
  if (kp == 0) {
#pragma unroll
    for (int ni = 0; ni < 8; ni++) {
      sred[wi][ni * 16 + lr] = s_part[ni];
      qred[wi][ni * 16 + lr] = q_part[ni];
    }
  }
  __syncthreads();
  if (t < 128) {
    float S = sred[0][t] + sred[1][t] + sred[2][t] + sred[3][t];
    float Q = qred[0][t] + qred[1][t] + qred[2][t] + qred[3][t];
    atomicAdd(&gsum[t], S);
    atomicAdd(&gsq[t], Q);
  }
}

__global__ void k_bnparams(const float* __restrict__ sum, const float* __restrict__ sumsq,
                           const float* __restrict__ gamma, const float* __restrict__ beta,
                           float* __restrict__ Ac, float* __restrict__ Bc,
                           int C, float invM) {
  int c = blockIdx.x * blockDim.x + threadIdx.x;
  if (c < C) {
    float mu = sum[c] * invM;
    float var = sumsq[c] * invM - mu * mu;
    float rs = rsqrtf(var + EPS_BN);
    float a = gamma[c] * rs;
    Ac[c] = a;
    Bc[c] = beta[c] - mu * a;
  }
}

// ---------------- graph readout: xg[g] = sum relu(y*A+B), sorted gids ----------------
__global__ __launch_bounds__(64) void k_readout(const uint* __restrict__ y,
                                                const int* __restrict__ gid,
                                                const float* __restrict__ Ac,
                                                const float* __restrict__ Bc,
                                                float* __restrict__ xg, int nNodes) {
  int l = threadIdx.x;
  int n0 = blockIdx.x * 64;
  int n1 = min(n0 + 64, nNodes);
  if (n0 >= nNodes) return;
  float A0 = Ac[2 * l], B0 = Bc[2 * l], A1 = Ac[2 * l + 1], B1 = Bc[2 * l + 1];
  float a0 = 0, a1 = 0;
  int cur = gid[n0];
  for (int n = n0; n < n1; n++) {
    int g = gid[n];
    if (g != cur) {
      atomicAdd(&xg[(size_t)cur * 128 + 2 * l], a0);
      atomicAdd(&xg[(size_t)cur * 128 + 2 * l + 1], a1);
      a0 = 0; a1 = 0; cur = g;
    }
    uint v = y[(size_t)n * 64 + l];
    a0 += fmaxf(bf_lo(v) * A0 + B0, 0.f);
    a1 += fmaxf(bf_hi(v) * A1 + B1, 0.f);
  }
  atomicAdd(&xg[(size_t)cur * 128 + 2 * l], a0);
  atomicAdd(&xg[(size_t)cur * 128 + 2 * l + 1], a1);
}

// ---------------- generic fp32 GEMM for MLP head (act: 0=none, 1=sigmoid) ----------------
#define KTILE 128
__global__ __launch_bounds__(256) void k_gemm(const float* __restrict__ A, int lda,
                                              int Mrows, int K,
                                              const float* __restrict__ W, int wld,
                                              int col_off,
                                              const float* __restrict__ bias,
                                              float* __restrict__ Y, int ncols, int act) {
  __shared__ float At[KTILE][36];
  __shared__ float Ws[KTILE][64];
  int t = threadIdx.x;
  int tx = t & 31;
  int ty = t >> 5;
  int r0 = blockIdx.y * 32;
  int c0 = blockIdx.x * 64;
  float acc[4][2] = {};

  for (int k0 = 0; k0 < K; k0 += KTILE) {
    int kt = min(KTILE, K - k0);
    for (int e = t; e < 32 * kt; e += 256) {
      int r = e / kt, k = e - r * kt;
      int gr = r0 + r;
      At[k][r] = (gr < Mrows) ? A[(size_t)gr * lda + k0 + k] : 0.0f;
    }
    for (int e = t; e < kt * 64; e += 256) {
      int k = e >> 6, c = e & 63;
      int gc = c0 + c;
      Ws[k][c] = (gc < ncols) ? W[(size_t)(k0 + k) * wld + col_off + gc] : 0.0f;
    }
    __syncthreads();
    for (int k = 0; k < kt; k++) {
      float4 a = *reinterpret_cast<const float4*>(&At[k][ty * 4]);
      float2 w = *reinterpret_cast<const float2*>(&Ws[k][tx * 2]);
      acc[0][0] += a.x * w.x; acc[0][1] += a.x * w.y;
      acc[1][0] += a.y * w.x; acc[1][1] += a.y * w.y;
      acc[2][0] += a.z * w.x; acc[2][1] += a.z * w.y;
      acc[3][0] += a.w * w.x; acc[3][1] += a.w * w.y;
    }
    __syncthreads();
  }

  for (int i = 0; i < 4; i++) {
    int r = r0 + ty * 4 + i;
    if (r >= Mrows) continue;
    for (int j = 0; j < 2; j++) {
      int c = c0 + tx * 2 + j;
      if (c < ncols) {
        float v = acc[i][j] + bias[col_off + c];
        if (act == 1) v = 1.0f / (1.0f + expf(-v));
        Y[(size_t)r * ncols + c] = v;
      }
    }
  }
}

__global__ void k_stats(const float* __restrict__ Y, int Mrows, int C,
                        float* __restrict__ sum, float* __restrict__ sumsq) {
  int c = threadIdx.x;
  float s = 0.0f, q = 0.0f;
  for (int r = blockIdx.x; r < Mrows; r += gridDim.x) {
    float v = Y[(size_t)r * C + c];
    s += v;
    q += v * v;
  }
  atomicAdd(&sum[c], s);
  atomicAdd(&sumsq[c], q);
}

__global__ void k_norm_relu(const float* __restrict__ Y, const float* __restrict__ Ac,
                            const float* __restrict__ Bc, float* __restrict__ X,
                            int total, int cmask) {
  int i = (blockIdx.x * blockDim.x + threadIdx.x) * 4;
  if (i < total) {
    float4 v = *reinterpret_cast<const float4*>(&Y[i]);
    int c = i & cmask;
    v.x = fmaxf(v.x * Ac[c] + Bc[c], 0.0f);
    v.y = fmaxf(v.y * Ac[c + 1] + Bc[c + 1], 0.0f);
    v.z = fmaxf(v.z * Ac[c + 2] + Bc[c + 2], 0.0f);
    v.w = fmaxf(v.w * Ac[c + 3] + Bc[c + 3], 0.0f);
    *reinterpret_cast<float4*>(&X[i]) = v;
  }
}

extern "C" void kernel_launch(void* const* d_in, const int* in_sizes, int n_in,
                              void* d_out, int out_size, void* d_ws, size_t ws_size,
                              hipStream_t stream) {
  const float* h    = (const float*)d_in[0];
  const int*   esrc = (const int*)d_in[1];
  const int*   edst = (const int*)d_in[2];
  const int*   gid  = (const int*)d_in[3];
  const float* W1   = (const float*)d_in[4];
  const float* b1   = (const float*)d_in[5];
  const float* g1g  = (const float*)d_in[6];
  const float* g1b  = (const float*)d_in[7];
  const float* Wg   = (const float*)d_in[8];
  const float* bg   = (const float*)d_in[9];
  const float* gg   = (const float*)d_in[10];
  const float* gb   = (const float*)d_in[11];
  const float* fc1W = (const float*)d_in[12];
  const float* fc1b = (const float*)d_in[13];
  const float* bn1g = (const float*)d_in[14];
  const float* bn1b = (const float*)d_in[15];
  const float* linW = (const float*)d_in[16];
  const float* linb = (const float*)d_in[17];
  const float* lbng = (const float*)d_in[18];
  const float* lbnb = (const float*)d_in[19];
  const float* fc2W = (const float*)d_in[20];
  const float* fc2b = (const float*)d_in[21];
  float* out = (float*)d_out;

  char* p = (char*)d_ws;
  auto alloc = [&](size_t bytes) {
    char* q = p;
    p += (bytes + 255) & ~(size_t)255;
    return q;
  };
  int* row_ptr = (int*)alloc((N_NODES + 1) * sizeof(int));
  int* cursor  = (int*)alloc(N_NODES * sizeof(int));   // degree buffer
  int* part    = (int*)alloc(128 * sizeof(int));
  int* bcur    = (int*)alloc(NBUCK * sizeof(int));
  int* csr     = (int*)alloc(N_EDGES * sizeof(int));
  uint* hb     = (uint*)alloc((size_t)N_NODES * 64 * sizeof(uint));
  uint* Mb     = (uint*)alloc((size_t)N_NODES * 64 * sizeof(uint));
  uint* yb     = (uint*)alloc((size_t)N_NODES * 64 * sizeof(uint));
  ushort* Wt   = (ushort*)alloc(5 * 128 * 128 * sizeof(ushort));
  float* ssum  = (float*)alloc(512 * sizeof(float));
  float* ssq   = (float*)alloc(512 * sizeof(float));
  float* Ac    = (float*)alloc(512 * sizeof(float));
  float* Bc    = (float*)alloc(512 * sizeof(float));
  float* xg    = (float*)alloc((size_t)N_GRAPHS * 128 * sizeof(float));
  float* y1    = (float*)alloc((size_t)N_GRAPHS * 512 * sizeof(float));
  float* x1    = (float*)alloc((size_t)N_GRAPHS * 512 * sizeof(float));
  float* y2    = (float*)alloc((size_t)N_GRAPHS * 256 * sizeof(float));
  float* x2    = (float*)alloc((size_t)N_GRAPHS * 256 * sizeof(float));
  // staging for binned scatter aliases Mb (dead until the layer loop)
  uint2* staging = (uint2*)Mb;  // N_EDGES * 8B = 12.8MB <= 25.6MB

  // ---- prep: conversions + CSR build ----
  k_conv_h<<<(N_NODES * 64 + 255) / 256, 256, 0, stream>>>(h, hb, N_NODES);
  k_prep_wt<<<64, 256, 0, stream>>>(W1, Wt, 78);
  for (int l = 0; l < 4; l++)
    k_prep_wt<<<64, 256, 0, stream>>>(Wg + (size_t)l * 128 * 128, Wt + (size_t)(l + 1) * 128 * 128, 128);

  const int NB = (N_NODES + 1023) / 1024;  // 98
  hipMemsetAsync(cursor, 0, N_NODES * sizeof(int), stream);
  k_degree<<<(N_EDGES + 255) / 256, 256, 0, stream>>>(edst, cursor, N_EDGES);
  k_scan_part<<<NB, 256, 0, stream>>>(cursor, part, N_NODES);
  k_scan_off<<<1, 128, 0, stream>>>(part, NB);
  k_scan_write<<<NB, 256, 0, stream>>>(cursor, part, row_ptr, N_NODES);
  k_init_cursor<<<(NBUCK + 255) / 256, 256, 0, stream>>>(row_ptr, bcur);
  k_bin<<<(N_EDGES + BIN_CHUNK - 1) / BIN_CHUNK, 256, 0, stream>>>(esrc, edst, bcur,
                                                                   staging, N_EDGES);
  k_place<<<NBUCK, 256, 0, stream>>>(staging, row_ptr, csr, N_NODES);

  const float invN = 1.0f / (float)N_NODES;
  const float invG = 1.0f / (float)N_GRAPHS;

  // ---- 5 GIN layers: agg(+prev BN/ReLU) -> MFMA GEMM(+stats) -> bnparams ----
  for (int layer = 0; layer < 5; layer++) {
    const ushort* Wl = Wt + (size_t)layer * 128 * 128;
    const float* bl  = (layer == 0) ? b1 : bg + (size_t)(layer - 1) * 128;
    const float* gl  = (layer == 0) ? g1g : gg + (size_t)(layer - 1) * 128;
    const float* bl2 = (layer == 0) ? g1b : gb + (size_t)(layer - 1) * 128;

    if (layer == 0)
      k_agg_f<false><<<(N_NODES + 3) / 4, 256, 0, stream>>>(hb, row_ptr, csr, nullptr, nullptr,
                                                            Mb, N_NODES);
    else
      k_agg_f<true><<<(N_NODES + 3) / 4, 256, 0, stream>>>(yb, row_ptr, csr, Ac, Bc,
                                                           Mb, N_NODES);
    hipMemsetAsync(ssum, 0, 128 * sizeof(float), stream);
    hipMemsetAsync(ssq, 0, 128 * sizeof(float), stream);
    k_gemm_mfma<<<(N_NODES + 127) / 128, 256, 0, stream>>>((const ushort*)Mb, Wl, bl, 2.0f,
                                                           (ushort*)yb, N_NODES, ssum, ssq);
    k_bnparams<<<1, 128, 0, stream>>>(ssum, ssq, gl, bl2, Ac, Bc, 128, invN);
  }

  // ---- readout (applies layer-5 BN+ReLU inline) ----
  hipMemsetAsync(xg, 0, (size_t)N_GRAPHS * 128 * sizeof(float), stream);
  k_readout<<<(N_NODES + 63) / 64, 64, 0, stream>>>(yb, gid, Ac, Bc, xg, N_NODES);

  // ---- fc1 (128 -> 512) + BN + relu ----
  {
    dim3 grid(8, N_GRAPHS / 32);
    k_gemm<<<grid, 256, 0, stream>>>(xg, 128, N_GRAPHS, 128, fc1W, 512, 0, fc1b, y1, 512, 0);
  }
  hipMemsetAsync(ssum, 0, 512 * sizeof(float), stream);
  hipMemsetAsync(ssq, 0, 512 * sizeof(float), stream);
  k_stats<<<256, 512, 0, stream>>>(y1, N_GRAPHS, 512, ssum, ssq);
  k_bnparams<<<1, 512, 0, stream>>>(ssum, ssq, bn1g, bn1b, Ac, Bc, 512, invG);
  k_norm_relu<<<(N_GRAPHS * 512 / 4 + 255) / 256, 256, 0, stream>>>(y1, Ac, Bc, x1,
                                                                    N_GRAPHS * 512, 511);

  // ---- lin (512 -> 256) + BN + relu ----
  {
    dim3 grid(4, N_GRAPHS / 32);
    k_gemm<<<grid, 256, 0, stream>>>(x1, 512, N_GRAPHS, 512, linW, 256, 0, linb, y2, 256, 0);
  }
  hipMemsetAsync(ssum, 0, 256 * sizeof(float), stream);
  hipMemsetAsync(ssq, 0, 256 * sizeof(float), stream);
  k_stats<<<256, 256, 0, stream>>>(y2, N_GRAPHS, 256, ssum, ssq);
  k_bnparams<<<1, 256, 0, stream>>>(ssum, ssq, lbng, lbnb, Ac, Bc, 256, invG);
  k_norm_relu<<<(N_GRAPHS * 256 / 4 + 255) / 256, 256, 0, stream>>>(y2, Ac, Bc, x2,
                                                                    N_GRAPHS * 256, 255);

  // ---- fc2: last 204 columns, sigmoid fused, write d_out ----
  {
    dim3 grid((NCLS + 63) / 64, N_GRAPHS / 32);
    k_gemm<<<grid, 256, 0, stream>>>(x2, 256, N_GRAPHS, 256, fc2W, 408, 204, fc2b, out,
                                     NCLS, 1);
  }
}

// Round 5
// 763.009 us; speedup vs baseline: 3.4913x; 1.0948x over previous
//
#include <hip/hip_runtime.h>
#include <hip/hip_bf16.h>
#include <math.h>

#define N_NODES 100000
#define N_EDGES 1600000
#define N_GRAPHS 2048
#define NCLS 204
#define EPS_BN 1e-5f
#define NBUCK ((N_NODES + 255) / 256)   // 391
#define BIN_CHUNK 8192

typedef __attribute__((ext_vector_type(8))) short short8;
typedef __attribute__((ext_vector_type(4))) float f32x4;

__device__ __forceinline__ float bf_lo(uint v) { union { uint i; float f; } c; c.i = v << 16; return c.f; }
__device__ __forceinline__ float bf_hi(uint v) { union { uint i; float f; } c; c.i = v & 0xffff0000u; return c.f; }
__device__ __forceinline__ ushort f2bf(float v) {
  __hip_bfloat16 b = __float2bfloat16(v);
  return *reinterpret_cast<ushort*>(&b);
}
__device__ __forceinline__ uint pack2(float a, float b) {
  return (uint)f2bf(a) | ((uint)f2bf(b) << 16);
}

// ---------------- CSR build ----------------
__global__ void k_degree(const int* __restrict__ dst, int* __restrict__ deg, int E) {
  int i = blockIdx.x * blockDim.x + threadIdx.x;
  if (i < E) atomicAdd(&deg[dst[i]], 1);
}

__global__ __launch_bounds__(256) void k_scan_part(const int* __restrict__ deg,
                                                   int* __restrict__ part, int n) {
  __shared__ int red[256];
  int t = threadIdx.x;
  int base = blockIdx.x * 1024 + t * 4;
  int s = 0;
  if (base + 4 <= n) {
    int4 v = *reinterpret_cast<const int4*>(deg + base);
    s = v.x + v.y + v.z + v.w;
  } else {
    for (int k = 0; k < 4; k++) if (base + k < n) s += deg[base + k];
  }
  red[t] = s;
  __syncthreads();
  for (int d = 128; d > 0; d >>= 1) {
    if (t < d) red[t] += red[t + d];
    __syncthreads();
  }
  if (t == 0) part[blockIdx.x] = red[0];
}

__global__ __launch_bounds__(128) void k_scan_off(int* __restrict__ part, int nb) {
  __shared__ int sh[128];
  int t = threadIdx.x;
  sh[t] = (t < nb) ? part[t] : 0;
  __syncthreads();
  for (int d = 1; d < 128; d <<= 1) {
    int v = (t >= d) ? sh[t - d] : 0;
    __syncthreads();
    sh[t] += v;
    __syncthreads();
  }
  if (t < nb) part[t] = (t == 0) ? 0 : sh[t - 1];
}

__global__ __launch_bounds__(256) void k_scan_write(const int* __restrict__ deg,
                                                    const int* __restrict__ part,
                                                    int* __restrict__ row_ptr, int n) {
  __shared__ int red[256];
  int t = threadIdx.x;
  int base = blockIdx.x * 1024 + t * 4;
  int v[4];
  int s = 0;
  for (int k = 0; k < 4; k++) {
    v[k] = (base + k < n) ? deg[base + k] : 0;
    s += v[k];
  }
  red[t] = s;
  __syncthreads();
  for (int d = 1; d < 256; d <<= 1) {
    int x = (t >= d) ? red[t - d] : 0;
    __syncthreads();
    red[t] += x;
    __syncthreads();
  }
  int run = part[blockIdx.x] + ((t == 0) ? 0 : red[t - 1]);
  for (int k = 0; k < 4; k++) {
    if (base + k < n) row_ptr[base + k] = run;
    run += v[k];
  }
  if (blockIdx.x == gridDim.x - 1 && t == 255) row_ptr[n] = run;
}

__global__ void k_init_cursor(const int* __restrict__ row_ptr, int* __restrict__ cursor) {
  int b = blockIdx.x * blockDim.x + threadIdx.x;
  if (b < NBUCK) cursor[b] = row_ptr[b * 256];
}

__global__ __launch_bounds__(256) void k_bin(const int* __restrict__ src,
                                             const int* __restrict__ dst,
                                             int* __restrict__ cursor,
                                             uint2* __restrict__ staging, int E) {
  __shared__ int hist[NBUCK];
  __shared__ int base_s[NBUCK];
  int t = threadIdx.x;
  int e0 = blockIdx.x * BIN_CHUNK;
  for (int b = t; b < NBUCK; b += 256) hist[b] = 0;
  __syncthreads();
  for (int e = e0 + t; e < min(e0 + BIN_CHUNK, E); e += 256)
    atomicAdd(&hist[dst[e] >> 8], 1);
  __syncthreads();
  for (int b = t; b < NBUCK; b += 256) {
    int hh = hist[b];
    if (hh > 0) base_s[b] = atomicAdd(&cursor[b], hh);
    hist[b] = 0;
  }
  __syncthreads();
  for (int e = e0 + t; e < min(e0 + BIN_CHUNK, E); e += 256) {
    int d = dst[e];
    int b = d >> 8;
    int r = atomicAdd(&hist[b], 1);
    staging[base_s[b] + r] = make_uint2((uint)src[e], (uint)d);
  }
}

__global__ __launch_bounds__(256) void k_place(const uint2* __restrict__ staging,
                                               const int* __restrict__ row_ptr,
                                               int* __restrict__ csr, int nNodes) {
  __shared__ int cur[256];
  int t = threadIdx.x;
  int n0 = blockIdx.x * 256;
  int nend = min(n0 + 256, nNodes);
  if (n0 + t < nend) cur[t] = row_ptr[n0 + t];
  __syncthreads();
  int s = row_ptr[n0];
  int e = row_ptr[nend];
  for (int i = s + t; i < e; i += 256) {
    uint2 ed = staging[i];
    int pos = atomicAdd(&cur[ed.y - n0], 1);
    csr[pos] = (int)ed.x;
  }
}

// ---------------- conversions / weight prep ----------------
__global__ void k_conv_h(const float* __restrict__ h, uint* __restrict__ hb, int nNodes) {
  int i = blockIdx.x * blockDim.x + threadIdx.x;
  if (i < nNodes * 64) {
    int n = i >> 6, cp = i & 63;
    int c = cp * 2;
    float a = (c < 78) ? h[(size_t)n * 78 + c] : 0.0f;
    float b = (c + 1 < 78) ? h[(size_t)n * 78 + c + 1] : 0.0f;
    hb[i] = pack2(a, b);
  }
}

__global__ void k_prep_wt(const float* __restrict__ W, ushort* __restrict__ Wt, int K) {
  int i = blockIdx.x * blockDim.x + threadIdx.x;
  if (i < 128 * 128) {
    int n = i >> 7, k = i & 127;
    float v = (k < K) ? W[(size_t)k * 128 + n] : 0.0f;
    Wt[i] = f2bf(v);
  }
}

// generic: W [K x wld] fp32, keep cols [col_off, col_off+nkeep) -> Wt bf16 [Npad x K]
__global__ void k_prep_wt_gen(const float* __restrict__ W, int wld, int col_off, int nkeep,
                              int K, ushort* __restrict__ Wt, int total) {
  int i = blockIdx.x * blockDim.x + threadIdx.x;
  if (i < total) {
    int n = i / K, k = i - n * K;
    float v = (n < nkeep) ? W[(size_t)k * wld + col_off + n] : 0.0f;
    Wt[i] = f2bf(v);
  }
}

// ---------------- GIN aggregation, fused with prev layer's BN+ReLU ----------------
template <bool NRM>
__global__ __launch_bounds__(256) void k_agg_f(const uint* __restrict__ y,
                                               const int* __restrict__ row_ptr,
                                               const int* __restrict__ csr,
                                               const float* __restrict__ Ac,
                                               const float* __restrict__ Bc,
                                               uint* __restrict__ M, int nNodes) {
  int n = blockIdx.x * 4 + (threadIdx.x >> 6);
  if (n >= nNodes) return;
  int l = threadIdx.x & 63;
  float A0 = 1.f, B0 = 0.f, A1 = 1.f, B1 = 0.f;
  if (NRM) { A0 = Ac[2 * l]; B0 = Bc[2 * l]; A1 = Ac[2 * l + 1]; B1 = Bc[2 * l + 1]; }

  auto flo = [&](uint v) { float x = bf_lo(v); return NRM ? fmaxf(x * A0 + B0, 0.f) : x; };
  auto fhi = [&](uint v) { float x = bf_hi(v); return NRM ? fmaxf(x * A1 + B1, 0.f) : x; };

  uint self = y[(size_t)n * 64 + l];
  float a0 = 2.0f * flo(self);
  float a1 = 2.0f * fhi(self);
  int s = row_ptr[n], e = row_ptr[n + 1];

  for (int base = s; base < e; base += 64) {
    int cnt = e - base;
    if (cnt > 64) cnt = 64;
    int myidx = (base + l < e) ? csr[base + l] : 0;
    int j = 0;
    for (; j + 4 <= cnt; j += 4) {
      int i0 = __shfl(myidx, j);
      int i1 = __shfl(myidx, j + 1);
      int i2 = __shfl(myidx, j + 2);
      int i3 = __shfl(myidx, j + 3);
      uint v0 = y[(size_t)i0 * 64 + l];
      uint v1 = y[(size_t)i1 * 64 + l];
      uint v2 = y[(size_t)i2 * 64 + l];
      uint v3 = y[(size_t)i3 * 64 + l];
      a0 += flo(v0) + flo(v1) + flo(v2) + flo(v3);
      a1 += fhi(v0) + fhi(v1) + fhi(v2) + fhi(v3);
    }
    for (; j < cnt; j++) {
      int i0 = __shfl(myidx, j);
      uint v = y[(size_t)i0 * 64 + l];
      a0 += flo(v);
      a1 += fhi(v);
    }
  }
  M[(size_t)n * 64 + l] = pack2(a0, a1);
}

// ---------------- node-layer MFMA GEMM + fused BN stats ----------------
#define SWZ(row, boff) ((boff) ^ (((row) & 7) << 4))
__global__ __launch_bounds__(256) void k_gemm_mfma(const ushort* __restrict__ A,
                                                   const ushort* __restrict__ Wt,
                                                   const float* __restrict__ bias, float bscale,
                                                   ushort* __restrict__ Y, int Mrows,
                                                   float* __restrict__ gsum,
                                                   float* __restrict__ gsq) {
  __shared__ ushort As[128 * 128];
  __shared__ ushort Bs[128 * 128];
  __shared__ float sred[4][128], qred[4][128];
  int t = threadIdx.x;
  int r0 = blockIdx.x * 128;
  char* Ab = (char*)As;
  char* Bb = (char*)Bs;

  for (int it = 0; it < 8; it++) {
    int e = it * 256 + t;
    int row = e >> 4, seg = e & 15;
    uint4 va = make_uint4(0, 0, 0, 0);
    int gr = r0 + row;
    if (gr < Mrows) va = *reinterpret_cast<const uint4*>(A + (size_t)gr * 128 + seg * 8);
    *reinterpret_cast<uint4*>(Ab + row * 256 + SWZ(row, seg * 16)) = va;
    uint4 vb = *reinterpret_cast<const uint4*>(Wt + (size_t)row * 128 + seg * 8);
    *reinterpret_cast<uint4*>(Bb + row * 256 + SWZ(row, seg * 16)) = vb;
  }
  __syncthreads();

  int wi = t >> 6;
  int l = t & 63;
  int lr = l & 15;
  int kp = l >> 4;

  f32x4 acc[2][8];
#pragma unroll
  for (int mi = 0; mi < 2; mi++)
#pragma unroll
    for (int ni = 0; ni < 8; ni++) acc[mi][ni] = (f32x4){0.f, 0.f, 0.f, 0.f};

#pragma unroll
  for (int ki = 0; ki < 4; ki++) {
    short8 a[2], b[8];
#pragma unroll
    for (int mi = 0; mi < 2; mi++) {
      int row = wi * 32 + mi * 16 + lr;
      a[mi] = *reinterpret_cast<const short8*>(Ab + row * 256 + SWZ(row, ki * 64 + kp * 16));
    }
#pragma unroll
    for (int ni = 0; ni < 8; ni++) {
      int row = ni * 16 + lr;
      b[ni] = *reinterpret_cast<const short8*>(Bb + row * 256 + SWZ(row, ki * 64 + kp * 16));
    }
#pragma unroll
    for (int mi = 0; mi < 2; mi++)
#pragma unroll
      for (int ni = 0; ni < 8; ni++)
        acc[mi][ni] = __builtin_amdgcn_mfma_f32_16x16x32_bf16(a[mi], b[ni], acc[mi][ni], 0, 0, 0);
  }

  float s_part[8], q_part[8];
#pragma unroll
  for (int ni = 0; ni < 8; ni++) { s_part[ni] = 0.f; q_part[ni] = 0.f; }

#pragma unroll
  for (int mi = 0; mi < 2; mi++) {
    int rbase = r0 + wi * 32 + mi * 16 + kp * 4;
#pragma unroll
    for (int ni = 0; ni < 8; ni++) {
      int col = ni * 16 + lr;
      float bb = bscale * bias[col];
#pragma unroll
      for (int j = 0; j < 4; j++) {
        int r = rbase + j;
        if (r < Mrows) {
          float yv = acc[mi][ni][j] + bb;
          Y[(size_t)r * 128 + col] = f2bf(yv);
          s_part[ni] += yv;
          q_part[ni] += yv * yv;
        }
      }
    }
  }

#pragma unroll
  for (int ni = 0; ni < 8; ni++) {
    s_part[ni] += __shfl_xor(s_part[ni], 16, 64);
    s_part[ni] += __shfl_xor(s_part[ni], 32, 64);
    q_part[ni] += __shfl_xor(q_part[ni], 16, 64);
    q_part[ni] += __shfl_xor(q_part[ni], 32, 64);
  }
  if (kp == 0) {
#pragma unroll
    for (int ni = 0; ni < 8; ni++) {
      sred[wi][ni * 16 + lr] = s_part[ni];
      qred[wi][ni * 16 + lr] = q_part[ni];
    }
  }
  __syncthreads();
  if (t < 128) {
    float S = sred[0][t] + sred[1][t] + sred[2][t] + sred[3][t];
    float Q = qred[0][t] + qred[1][t] + qred[2][t] + qred[3][t];
    atomicAdd(&gsum[t], S);
    atomicAdd(&gsq[t], Q);
  }
}

// ---------------- head MFMA GEMM (generic M,K; 128x128 tiles) ----------------
// AMODE 0: A fp32 [M x K], convert to bf16 inline.
// AMODE 1: A bf16-packed uint [M x K/2], apply relu(v*nAc+nBc) inline.
// OMODE 0: write Y bf16 [M x Nld] + fused BN stats into gsum/gsq at col c0+t.
// OMODE 1: write fp32 sigmoid(acc+bias) to Yout [M x Nld], cols < ncols only.
template <int AMODE, int OMODE>
__global__ __launch_bounds__(256) void k_head_mfma(const void* __restrict__ Aptr,
                                                   int Mrows, int K,
                                                   const ushort* __restrict__ Wt,
                                                   const float* __restrict__ bias,
                                                   int col_off, int ncols,
                                                   const float* __restrict__ nAc,
                                                   const float* __restrict__ nBc,
                                                   void* __restrict__ Yout, int Nld,
                                                   float* __restrict__ gsum,
                                                   float* __restrict__ gsq) {
  __shared__ ushort As[128 * 128];
  __shared__ ushort Bs[128 * 128];
  __shared__ float sred[4][128], qred[4][128];
  int t = threadIdx.x;
  int r0 = blockIdx.y * 128;
  int c0 = blockIdx.x * 128;
  char* Ab = (char*)As;
  char* Bb = (char*)Bs;

  int wi = t >> 6;
  int l = t & 63;
  int lr = l & 15;
  int kp = l >> 4;

  f32x4 acc[2][8];
#pragma unroll
  for (int mi = 0; mi < 2; mi++)
#pragma unroll
    for (int ni = 0; ni < 8; ni++) acc[mi][ni] = (f32x4){0.f, 0.f, 0.f, 0.f};

  for (int k0 = 0; k0 < K; k0 += 128) {
    if (k0) __syncthreads();
    for (int it = 0; it < 8; it++) {
      int e = it * 256 + t;
      int row = e >> 4, seg = e & 15;
      int gr = r0 + row;
      uint4 va;
      if (AMODE == 0) {
        const float* Af = (const float*)Aptr;
        float4 f0 = {0.f, 0.f, 0.f, 0.f}, f1 = {0.f, 0.f, 0.f, 0.f};
        if (gr < Mrows) {
          f0 = *reinterpret_cast<const float4*>(Af + (size_t)gr * K + k0 + seg * 8);
          f1 = *reinterpret_cast<const float4*>(Af + (size_t)gr * K + k0 + seg * 8 + 4);
        }
        va.x = pack2(f0.x, f0.y); va.y = pack2(f0.z, f0.w);
        va.z = pack2(f1.x, f1.y); va.w = pack2(f1.z, f1.w);
      } else {
        const uint* Au = (const uint*)Aptr;
        uint4 r4 = make_uint4(0, 0, 0, 0);
        if (gr < Mrows) r4 = *reinterpret_cast<const uint4*>(Au + (size_t)gr * (K >> 1) + ((k0 + seg * 8) >> 1));
        int c = k0 + seg * 8;
        uint uu[4] = {r4.x, r4.y, r4.z, r4.w};
#pragma unroll
        for (int q = 0; q < 4; q++) {
          float aa = fmaxf(bf_lo(uu[q]) * nAc[c + 2 * q] + nBc[c + 2 * q], 0.f);
          float bb = fmaxf(bf_hi(uu[q]) * nAc[c + 2 * q + 1] + nBc[c + 2 * q + 1], 0.f);
          uu[q] = pack2(aa, bb);
        }
        va = make_uint4(uu[0], uu[1], uu[2], uu[3]);
      }
      *reinterpret_cast<uint4*>(Ab + row * 256 + SWZ(row, seg * 16)) = va;
      uint4 vb = *reinterpret_cast<const uint4*>(Wt + (size_t)(c0 + row) * K + k0 + seg * 8);
      *reinterpret_cast<uint4*>(Bb + row * 256 + SWZ(row, seg * 16)) = vb;
    }
    __syncthreads();

#pragma unroll
    for (int ki = 0; ki < 4; ki++) {
      short8 a[2], b[8];
#pragma unroll
      for (int mi = 0; mi < 2; mi++) {
        int row = wi * 32 + mi * 16 + lr;
        a[mi] = *reinterpret_cast<const short8*>(Ab + row * 256 + SWZ(row, ki * 64 + kp * 16));
      }
#pragma unroll
      for (int ni = 0; ni < 8; ni++) {
        int row = ni * 16 + lr;
        b[ni] = *reinterpret_cast<const short8*>(Bb + row * 256 + SWZ(row, ki * 64 + kp * 16));
      }
#pragma unroll
      for (int mi = 0; mi < 2; mi++)
#pragma unroll
        for (int ni = 0; ni < 8; ni++)
          acc[mi][ni] = __builtin_amdgcn_mfma_f32_16x16x32_bf16(a[mi], b[ni], acc[mi][ni], 0, 0, 0);
    }
  }

  if (OMODE == 0) {
    float s_part[8], q_part[8];
#pragma unroll
    for (int ni = 0; ni < 8; ni++) { s_part[ni] = 0.f; q_part[ni] = 0.f; }
#pragma unroll
    for (int mi = 0; mi < 2; mi++) {
      int rbase = r0 + wi * 32 + mi * 16 + kp * 4;
#pragma unroll
      for (int ni = 0; ni < 8; ni++) {
        int gc = c0 + ni * 16 + lr;
        float bb = bias[col_off + gc];
#pragma unroll
        for (int j = 0; j < 4; j++) {
          int r = rbase + j;
          if (r < Mrows) {
            float yv = acc[mi][ni][j] + bb;
            ((ushort*)Yout)[(size_t)r * Nld + gc] = f2bf(yv);
            s_part[ni] += yv;
            q_part[ni] += yv * yv;
          }
        }
      }
    }
#pragma unroll
    for (int ni = 0; ni < 8; ni++) {
      s_part[ni] += __shfl_xor(s_part[ni], 16, 64);
      s_part[ni] += __shfl_xor(s_part[ni], 32, 64);
      q_part[ni] += __shfl_xor(q_part[ni], 16, 64);
      q_part[ni] += __shfl_xor(q_part[ni], 32, 64);
    }
    if (kp == 0) {
#pragma unroll
      for (int ni = 0; ni < 8; ni++) {
        sred[wi][ni * 16 + lr] = s_part[ni];
        qred[wi][ni * 16 + lr] = q_part[ni];
      }
    }
    __syncthreads();
    if (t < 128) {
      float S = sred[0][t] + sred[1][t] + sred[2][t] + sred[3][t];
      float Q = qred[0][t] + qred[1][t] + qred[2][t] + qred[3][t];
      atomicAdd(&gsum[c0 + t], S);
      atomicAdd(&gsq[c0 + t], Q);
    }
  } else {
#pragma unroll
    for (int mi = 0; mi < 2; mi++) {
      int rbase = r0 + wi * 32 + mi * 16 + kp * 4;
#pragma unroll
      for (int ni = 0; ni < 8; ni++) {
        int gc = c0 + ni * 16 + lr;
        if (gc < ncols) {
          float bb = bias[col_off + gc];
#pragma unroll
          for (int j = 0; j < 4; j++) {
            int r = rbase + j;
            if (r < Mrows) {
              float v = acc[mi][ni][j] + bb;
              ((float*)Yout)[(size_t)r * Nld + gc] = 1.0f / (1.0f + expf(-v));
            }
          }
        }
      }
    }
  }
}

__global__ void k_bnparams(const float* __restrict__ sum, const float* __restrict__ sumsq,
                           const float* __restrict__ gamma, const float* __restrict__ beta,
                           float* __restrict__ Ac, float* __restrict__ Bc,
                           int C, float invM) {
  int c = blockIdx.x * blockDim.x + threadIdx.x;
  if (c < C) {
    float mu = sum[c] * invM;
    float var = sumsq[c] * invM - mu * mu;
    float rs = rsqrtf(var + EPS_BN);
    float a = gamma[c] * rs;
    Ac[c] = a;
    Bc[c] = beta[c] - mu * a;
  }
}

// ---------------- graph readout: xg[g] = sum relu(y*A+B), sorted gids ----------------
__global__ __launch_bounds__(64) void k_readout(const uint* __restrict__ y,
                                                const int* __restrict__ gid,
                                                const float* __restrict__ Ac,
                                                const float* __restrict__ Bc,
                                                float* __restrict__ xg, int nNodes) {
  int l = threadIdx.x;
  int n0 = blockIdx.x * 64;
  int n1 = min(n0 + 64, nNodes);
  if (n0 >= nNodes) return;
  float A0 = Ac[2 * l], B0 = Bc[2 * l], A1 = Ac[2 * l + 1], B1 = Bc[2 * l + 1];
  float a0 = 0, a1 = 0;
  int cur = gid[n0];
  for (int n = n0; n < n1; n++) {
    int g = gid[n];
    if (g != cur) {
      atomicAdd(&xg[(size_t)cur * 128 + 2 * l], a0);
      atomicAdd(&xg[(size_t)cur * 128 + 2 * l + 1], a1);
      a0 = 0; a1 = 0; cur = g;
    }
    uint v = y[(size_t)n * 64 + l];
    a0 += fmaxf(bf_lo(v) * A0 + B0, 0.f);
    a1 += fmaxf(bf_hi(v) * A1 + B1, 0.f);
  }
  atomicAdd(&xg[(size_t)cur * 128 + 2 * l], a0);
  atomicAdd(&xg[(size_t)cur * 128 + 2 * l + 1], a1);
}

extern "C" void kernel_launch(void* const* d_in, const int* in_sizes, int n_in,
                              void* d_out, int out_size, void* d_ws, size_t ws_size,
                              hipStream_t stream) {
  const float* h    = (const float*)d_in[0];
  const int*   esrc = (const int*)d_in[1];
  const int*   edst = (const int*)d_in[2];
  const int*   gid  = (const int*)d_in[3];
  const float* W1   = (const float*)d_in[4];
  const float* b1   = (const float*)d_in[5];
  const float* g1g  = (const float*)d_in[6];
  const float* g1b  = (const float*)d_in[7];
  const float* Wg   = (const float*)d_in[8];
  const float* bg   = (const float*)d_in[9];
  const float* gg   = (const float*)d_in[10];
  const float* gb   = (const float*)d_in[11];
  const float* fc1W = (const float*)d_in[12];
  const float* fc1b = (const float*)d_in[13];
  const float* bn1g = (const float*)d_in[14];
  const float* bn1b = (const float*)d_in[15];
  const float* linW = (const float*)d_in[16];
  const float* linb = (const float*)d_in[17];
  const float* lbng = (const float*)d_in[18];
  const float* lbnb = (const float*)d_in[19];
  const float* fc2W = (const float*)d_in[20];
  const float* fc2b = (const float*)d_in[21];
  float* out = (float*)d_out;

  char* p = (char*)d_ws;
  auto alloc = [&](size_t bytes) {
    char* q = p;
    p += (bytes + 255) & ~(size_t)255;
    return q;
  };
  int* row_ptr = (int*)alloc((N_NODES + 1) * sizeof(int));
  int* cursor  = (int*)alloc(N_NODES * sizeof(int));
  int* part    = (int*)alloc(128 * sizeof(int));
  int* bcur    = (int*)alloc(NBUCK * sizeof(int));
  int* csr     = (int*)alloc(N_EDGES * sizeof(int));
  uint* hb     = (uint*)alloc((size_t)N_NODES * 64 * sizeof(uint));
  uint* Mb     = (uint*)alloc((size_t)N_NODES * 64 * sizeof(uint));
  uint* yb     = (uint*)alloc((size_t)N_NODES * 64 * sizeof(uint));
  ushort* Wt   = (ushort*)alloc(5 * 128 * 128 * sizeof(ushort));
  ushort* fc1Wt = (ushort*)alloc(512 * 128 * sizeof(ushort));
  ushort* linWt = (ushort*)alloc(256 * 512 * sizeof(ushort));
  ushort* fc2Wt = (ushort*)alloc(256 * 256 * sizeof(ushort));
  float* ssum  = (float*)alloc(512 * sizeof(float));
  float* ssq   = (float*)alloc(512 * sizeof(float));
  float* Ac    = (float*)alloc(512 * sizeof(float));
  float* Bc    = (float*)alloc(512 * sizeof(float));
  float* xg    = (float*)alloc((size_t)N_GRAPHS * 128 * sizeof(float));
  uint* y1b    = (uint*)alloc((size_t)N_GRAPHS * 256 * sizeof(uint));  // bf16 G x 512
  uint* y2b    = (uint*)alloc((size_t)N_GRAPHS * 128 * sizeof(uint));  // bf16 G x 256
  uint2* staging = (uint2*)Mb;  // aliases Mb (dead until layer loop)

  // ---- prep: conversions + CSR build ----
  k_conv_h<<<(N_NODES * 64 + 255) / 256, 256, 0, stream>>>(h, hb, N_NODES);
  k_prep_wt<<<64, 256, 0, stream>>>(W1, Wt, 78);
  for (int l = 0; l < 4; l++)
    k_prep_wt<<<64, 256, 0, stream>>>(Wg + (size_t)l * 128 * 128, Wt + (size_t)(l + 1) * 128 * 128, 128);
  k_prep_wt_gen<<<(512 * 128 + 255) / 256, 256, 0, stream>>>(fc1W, 512, 0, 512, 128, fc1Wt, 512 * 128);
  k_prep_wt_gen<<<(256 * 512 + 255) / 256, 256, 0, stream>>>(linW, 256, 0, 256, 512, linWt, 256 * 512);
  k_prep_wt_gen<<<(256 * 256 + 255) / 256, 256, 0, stream>>>(fc2W, 408, 204, 204, 256, fc2Wt, 256 * 256);

  const int NB = (N_NODES + 1023) / 1024;
  hipMemsetAsync(cursor, 0, N_NODES * sizeof(int), stream);
  k_degree<<<(N_EDGES + 255) / 256, 256, 0, stream>>>(edst, cursor, N_EDGES);
  k_scan_part<<<NB, 256, 0, stream>>>(cursor, part, N_NODES);
  k_scan_off<<<1, 128, 0, stream>>>(part, NB);
  k_scan_write<<<NB, 256, 0, stream>>>(cursor, part, row_ptr, N_NODES);
  k_init_cursor<<<(NBUCK + 255) / 256, 256, 0, stream>>>(row_ptr, bcur);
  k_bin<<<(N_EDGES + BIN_CHUNK - 1) / BIN_CHUNK, 256, 0, stream>>>(esrc, edst, bcur,
                                                                   staging, N_EDGES);
  k_place<<<NBUCK, 256, 0, stream>>>(staging, row_ptr, csr, N_NODES);

  const float invN = 1.0f / (float)N_NODES;
  const float invG = 1.0f / (float)N_GRAPHS;

  // ---- 5 GIN layers ----
  for (int layer = 0; layer < 5; layer++) {
    const ushort* Wl = Wt + (size_t)layer * 128 * 128;
    const float* bl  = (layer == 0) ? b1 : bg + (size_t)(layer - 1) * 128;
    const float* gl  = (layer == 0) ? g1g : gg + (size_t)(layer - 1) * 128;
    const float* bl2 = (layer == 0) ? g1b : gb + (size_t)(layer - 1) * 128;

    if (layer == 0)
      k_agg_f<false><<<(N_NODES + 3) / 4, 256, 0, stream>>>(hb, row_ptr, csr, nullptr, nullptr,
                                                            Mb, N_NODES);
    else
      k_agg_f<true><<<(N_NODES + 3) / 4, 256, 0, stream>>>(yb, row_ptr, csr, Ac, Bc,
                                                           Mb, N_NODES);
    hipMemsetAsync(ssum, 0, 128 * sizeof(float), stream);
    hipMemsetAsync(ssq, 0, 128 * sizeof(float), stream);
    k_gemm_mfma<<<(N_NODES + 127) / 128, 256, 0, stream>>>((const ushort*)Mb, Wl, bl, 2.0f,
                                                           (ushort*)yb, N_NODES, ssum, ssq);
    k_bnparams<<<1, 128, 0, stream>>>(ssum, ssq, gl, bl2, Ac, Bc, 128, invN);
  }

  // ---- readout (applies layer-5 BN+ReLU inline) ----
  hipMemsetAsync(xg, 0, (size_t)N_GRAPHS * 128 * sizeof(float), stream);
  k_readout<<<(N_NODES + 63) / 64, 64, 0, stream>>>(yb, gid, Ac, Bc, xg, N_NODES);

  // ---- fc1 (128 -> 512): fp32 A, fused stats ----
  hipMemsetAsync(ssum, 0, 512 * sizeof(float), stream);
  hipMemsetAsync(ssq, 0, 512 * sizeof(float), stream);
  k_head_mfma<0, 0><<<dim3(4, 16), 256, 0, stream>>>(xg, N_GRAPHS, 128, fc1Wt, fc1b, 0, 512,
                                                     nullptr, nullptr, y1b, 512, ssum, ssq);
  k_bnparams<<<1, 512, 0, stream>>>(ssum, ssq, bn1g, bn1b, Ac, Bc, 512, invG);

  // ---- lin (512 -> 256): bf16 A + inline bn1/relu, fused stats ----
  hipMemsetAsync(ssum, 0, 256 * sizeof(float), stream);
  hipMemsetAsync(ssq, 0, 256 * sizeof(float), stream);
  k_head_mfma<1, 0><<<dim3(2, 16), 256, 0, stream>>>(y1b, N_GRAPHS, 512, linWt, linb, 0, 256,
                                                     Ac, Bc, y2b, 256, ssum, ssq);
  k_bnparams<<<1, 256, 0, stream>>>(ssum, ssq, lbng, lbnb, Ac, Bc, 256, invG);

  // ---- fc2 (256 -> 204): bf16 A + inline lbn/relu, sigmoid, write out ----
  k_head_mfma<1, 1><<<dim3(2, 16), 256, 0, stream>>>(y2b, N_GRAPHS, 256, fc2Wt, fc2b, 204, NCLS,
                                                     Ac, Bc, out, NCLS, nullptr, nullptr);
}